// Round 1
// baseline (2644.578 us; speedup 1.0000x reference)
//
#include <hip/hip_runtime.h>

#define N_NODES 100000
#define M_HYPER 50000
#define N_TOTAL 150000
#define D_IN    512
#define H_LAT   256
#define N_CLASS 40
#define NNZ_E   4800000
#define CNT_PAD 151552   // 37 * 4096, >= N_TOTAL+1

typedef float  floatx4 __attribute__((ext_vector_type(4)));
typedef __bf16 bf16x8  __attribute__((ext_vector_type(8)));

__device__ __forceinline__ unsigned short bf16_rne(float f) {
    unsigned u = __float_as_uint(f);
    return (unsigned short)((u + 0x7FFFu + ((u >> 16) & 1u)) >> 16);
}
__device__ __forceinline__ float bf16_hi_to_f32(unsigned bits_hi16_in_place) {
    return __uint_as_float(bits_hi16_in_place);
}

union FragU {
    unsigned short s[8];
    bf16x8 v;
};

// ---------------- W_red transpose + bf16 convert: W[512][256] -> WT[256][512] ----------------
__global__ void __launch_bounds__(256) prep_wt_kernel(const float* __restrict__ W,
                                                      unsigned short* __restrict__ WT) {
    int t = blockIdx.x * 256 + threadIdx.x;      // 0 .. 512*256-1
    if (t < D_IN * H_LAT) {
        int k = t >> 8;          // 0..511
        int n = t & 255;         // 0..255
        WT[n * D_IN + k] = bf16_rne(W[t]);
    }
}

// ---------------- GEMM1: emb = X @ W_red + b_red  (bf16 MFMA, fp32 X converted on the fly) ----
// one wave computes 32 rows x 256 cols. 4688 waves -> 1172 blocks of 256.
__global__ void __launch_bounds__(256) gemm1_kernel(const float* __restrict__ X,
                                                    const unsigned short* __restrict__ WT,
                                                    const float* __restrict__ brd,
                                                    unsigned short* __restrict__ emb) {
    int wid  = (blockIdx.x * 256 + threadIdx.x) >> 6;
    int lane = threadIdx.x & 63;
    int l16  = lane & 15;
    int quad = lane >> 4;
    int row0 = wid * 32;
    if (row0 >= N_TOTAL) return;

    int ra = min(row0 + l16,      N_TOTAL - 1);
    int rb = min(row0 + 16 + l16, N_TOTAL - 1);

    floatx4 acc0[16], acc1[16];
#pragma unroll
    for (int nt = 0; nt < 16; ++nt) { acc0[nt] = (floatx4)0.f; acc1[nt] = (floatx4)0.f; }

    const float* xpa = X + (size_t)ra * D_IN + quad * 8;
    const float* xpb = X + (size_t)rb * D_IN + quad * 8;
    const unsigned short* wp = WT + l16 * D_IN + quad * 8;

    for (int kt = 0; kt < 16; ++kt) {
        float4 a0 = *(const float4*)xpa;
        float4 a1 = *(const float4*)(xpa + 4);
        float4 b0 = *(const float4*)xpb;
        float4 b1 = *(const float4*)(xpb + 4);
        FragU ua, ub;
        ua.s[0] = bf16_rne(a0.x); ua.s[1] = bf16_rne(a0.y); ua.s[2] = bf16_rne(a0.z); ua.s[3] = bf16_rne(a0.w);
        ua.s[4] = bf16_rne(a1.x); ua.s[5] = bf16_rne(a1.y); ua.s[6] = bf16_rne(a1.z); ua.s[7] = bf16_rne(a1.w);
        ub.s[0] = bf16_rne(b0.x); ub.s[1] = bf16_rne(b0.y); ub.s[2] = bf16_rne(b0.z); ub.s[3] = bf16_rne(b0.w);
        ub.s[4] = bf16_rne(b1.x); ub.s[5] = bf16_rne(b1.y); ub.s[6] = bf16_rne(b1.z); ub.s[7] = bf16_rne(b1.w);
        bf16x8 fa = ua.v, fb = ub.v;

        const unsigned short* w2 = wp;
#pragma unroll
        for (int nt = 0; nt < 16; ++nt) {
            bf16x8 bw = *(const bf16x8*)w2;
            acc0[nt] = __builtin_amdgcn_mfma_f32_16x16x32_bf16(fa, bw, acc0[nt], 0, 0, 0);
            acc1[nt] = __builtin_amdgcn_mfma_f32_16x16x32_bf16(fb, bw, acc1[nt], 0, 0, 0);
            w2 += 16 * D_IN;
        }
        xpa += 32; xpb += 32; wp += 32;
    }

    // epilogue: C layout col = lane&15 (+16*nt), row = quad*4 + reg
#pragma unroll
    for (int nt = 0; nt < 16; ++nt) {
        int col = nt * 16 + l16;
        float bias = brd[col];
#pragma unroll
        for (int r = 0; r < 4; ++r) {
            int row = row0 + quad * 4 + r;
            if (row < N_TOTAL)      emb[(size_t)row * H_LAT + col]        = bf16_rne(acc0[nt][r] + bias);
            if (row + 16 < N_TOTAL) emb[(size_t)(row + 16) * H_LAT + col] = bf16_rne(acc1[nt][r] + bias);
        }
    }
}

// ---------------- CSR build ----------------
__global__ void __launch_bounds__(256) hist_kernel(const int* __restrict__ rows, int* __restrict__ cnt) {
    int e = blockIdx.x * 256 + threadIdx.x;
    if (e < NNZ_E) atomicAdd(&cnt[rows[e]], 1);
}

// single-block exclusive scan over CNT_PAD padded counters (zeros beyond N_TOTAL),
// writes row_ptr and a scratch copy row_ofs. row_ptr[N_TOTAL] lands = NNZ.
__global__ void __launch_bounds__(1024) scan_kernel(const int* __restrict__ cnt,
                                                    int* __restrict__ row_ptr,
                                                    int* __restrict__ row_ofs) {
    __shared__ int wsum[16];
    int tid = threadIdx.x;
    int lane = tid & 63, wid = tid >> 6;
    int running = 0;
    for (int base = 0; base < CNT_PAD; base += 4096) {
        int idx = base + tid * 4;
        int4 v = *(const int4*)(cnt + idx);
        int t0 = v.x, t1 = t0 + v.y, t2 = t1 + v.z, t3 = t2 + v.w;
        int tsum = t3;
        int s = tsum;
#pragma unroll
        for (int d = 1; d < 64; d <<= 1) {
            int o = __shfl_up(s, d);
            if (lane >= d) s += o;
        }
        if (lane == 63) wsum[wid] = s;
        __syncthreads();
        if (wid == 0) {
            int ws = (lane < 16) ? wsum[lane] : 0;
#pragma unroll
            for (int d = 1; d < 16; d <<= 1) {
                int o = __shfl_up(ws, d);
                if (lane >= d) ws += o;
            }
            if (lane < 16) wsum[lane] = ws;
        }
        __syncthreads();
        int waveoff = (wid == 0) ? 0 : wsum[wid - 1];
        int total   = wsum[15];
        int eb = running + waveoff + (s - tsum);
        int4 o4 = make_int4(eb, eb + t0, eb + t1, eb + t2);
        *(int4*)(row_ptr + idx) = o4;
        *(int4*)(row_ofs + idx) = o4;
        running += total;
        __syncthreads();
    }
}

__global__ void __launch_bounds__(256) scatter_kernel(const int* __restrict__ rows,
                                                      const int* __restrict__ cols,
                                                      const float* __restrict__ vals,
                                                      int* __restrict__ row_ofs,
                                                      int* __restrict__ csr_col,
                                                      float* __restrict__ csr_val) {
    int e = blockIdx.x * 256 + threadIdx.x;
    if (e < NNZ_E) {
        int r = rows[e];
        int p = atomicAdd(&row_ofs[r], 1);
        csr_col[p] = cols[e];
        csr_val[p] = vals[e];
    }
}

// ---------------- SpMM: cout[r,:] = sum_e val[e] * cin[col[e],:]  (one wave per row) ----------
__global__ void __launch_bounds__(256) spmm_kernel(const unsigned short* __restrict__ cin,
                                                   unsigned short* __restrict__ cout,
                                                   const int* __restrict__ row_ptr,
                                                   const int* __restrict__ csr_col,
                                                   const float* __restrict__ csr_val) {
    int r = (blockIdx.x * 256 + threadIdx.x) >> 6;
    if (r >= N_TOTAL) return;
    int lane = threadIdx.x & 63;
    int beg = row_ptr[r], end = row_ptr[r + 1];

    float a0 = 0.f, a1 = 0.f, a2 = 0.f, a3 = 0.f;
    const unsigned short* basep = cin + lane * 4;

    for (int b = beg; b < end; b += 64) {
        int e = b + lane;
        int c = 0; float v = 0.f;
        if (e < end) { c = csr_col[e]; v = csr_val[e]; }
        int n = min(64, end - b);
        for (int i = 0; i < n; ++i) {
            int   cc = __shfl(c, i);
            float vv = __shfl(v, i);
            uint2 g = *(const uint2*)(basep + (size_t)cc * H_LAT);
            a0 = fmaf(vv, __uint_as_float(g.x << 16),          a0);
            a1 = fmaf(vv, __uint_as_float(g.x & 0xFFFF0000u),  a1);
            a2 = fmaf(vv, __uint_as_float(g.y << 16),          a2);
            a3 = fmaf(vv, __uint_as_float(g.y & 0xFFFF0000u),  a3);
        }
    }
    unsigned r01 = (unsigned)bf16_rne(a0) | ((unsigned)bf16_rne(a1) << 16);
    unsigned r23 = (unsigned)bf16_rne(a2) | ((unsigned)bf16_rne(a3) << 16);
    uint2 o; o.x = r01; o.y = r23;
    *(uint2*)(cout + (size_t)r * H_LAT + lane * 4) = o;
}

// ---------------- fused classifier: Z = ((emb+c1+c2+c3)/4) @ W_cls + b_cls; log_softmax -------
__global__ void __launch_bounds__(256) cls_kernel(const unsigned short* __restrict__ emb,
                                                  const unsigned short* __restrict__ c1,
                                                  const unsigned short* __restrict__ c2,
                                                  const unsigned short* __restrict__ c3,
                                                  const float* __restrict__ W,
                                                  const float* __restrict__ bc,
                                                  float* __restrict__ out) {
    __shared__ float Wl[H_LAT * N_CLASS];
    __shared__ float bl[N_CLASS];
    for (int i = threadIdx.x; i < H_LAT * N_CLASS; i += 256) Wl[i] = W[i];
    if (threadIdx.x < N_CLASS) bl[threadIdx.x] = bc[threadIdx.x];
    __syncthreads();

    int r = blockIdx.x * 256 + threadIdx.x;
    if (r >= N_NODES) return;

    float Z[N_CLASS];
#pragma unroll
    for (int c = 0; c < N_CLASS; ++c) Z[c] = bl[c];

    const unsigned short* p0 = emb + (size_t)r * H_LAT;
    const unsigned short* p1 = c1 + (size_t)r * H_LAT;
    const unsigned short* p2 = c2 + (size_t)r * H_LAT;
    const unsigned short* p3 = c3 + (size_t)r * H_LAT;

    for (int f = 0; f < H_LAT; f += 4) {
        uint2 g0 = *(const uint2*)(p0 + f);
        uint2 g1 = *(const uint2*)(p1 + f);
        uint2 g2 = *(const uint2*)(p2 + f);
        uint2 g3 = *(const uint2*)(p3 + f);
        float af[4];
        af[0] = 0.25f * (__uint_as_float(g0.x << 16) + __uint_as_float(g1.x << 16) +
                         __uint_as_float(g2.x << 16) + __uint_as_float(g3.x << 16));
        af[1] = 0.25f * (__uint_as_float(g0.x & 0xFFFF0000u) + __uint_as_float(g1.x & 0xFFFF0000u) +
                         __uint_as_float(g2.x & 0xFFFF0000u) + __uint_as_float(g3.x & 0xFFFF0000u));
        af[2] = 0.25f * (__uint_as_float(g0.y << 16) + __uint_as_float(g1.y << 16) +
                         __uint_as_float(g2.y << 16) + __uint_as_float(g3.y << 16));
        af[3] = 0.25f * (__uint_as_float(g0.y & 0xFFFF0000u) + __uint_as_float(g1.y & 0xFFFF0000u) +
                         __uint_as_float(g2.y & 0xFFFF0000u) + __uint_as_float(g3.y & 0xFFFF0000u));
#pragma unroll
        for (int j = 0; j < 4; ++j) {
            const float* wrow = &Wl[(f + j) * N_CLASS];
#pragma unroll
            for (int c = 0; c < N_CLASS; ++c) Z[c] = fmaf(af[j], wrow[c], Z[c]);
        }
    }

    float m = Z[0];
#pragma unroll
    for (int c = 1; c < N_CLASS; ++c) m = fmaxf(m, Z[c]);
    float s = 0.f;
#pragma unroll
    for (int c = 0; c < N_CLASS; ++c) s += __expf(Z[c] - m);
    float ls = __logf(s) + m;
#pragma unroll
    for (int c = 0; c < N_CLASS; ++c) out[(size_t)r * N_CLASS + c] = Z[c] - ls;
}

// ---------------- launch ----------------
extern "C" void kernel_launch(void* const* d_in, const int* in_sizes, int n_in,
                              void* d_out, int out_size, void* d_ws, size_t ws_size,
                              hipStream_t stream) {
    const float* X        = (const float*)d_in[0];
    const float* W_red    = (const float*)d_in[1];
    const float* b_red    = (const float*)d_in[2];
    const float* W_cls    = (const float*)d_in[3];
    const float* b_cls    = (const float*)d_in[4];
    const float* e_vals   = (const float*)d_in[5];
    const int*   e_rows   = (const int*)d_in[6];
    const int*   e_cols   = (const int*)d_in[7];
    float* out = (float*)d_out;

    char* p = (char*)d_ws;
    auto carve = [&](size_t bytes) -> void* {
        void* r = (void*)p;
        p += (bytes + 255) & ~(size_t)255;
        return r;
    };
    unsigned short* WT   = (unsigned short*)carve((size_t)H_LAT * D_IN * 2);
    unsigned short* emb  = (unsigned short*)carve((size_t)N_TOTAL * H_LAT * 2);
    unsigned short* cb1  = (unsigned short*)carve((size_t)N_TOTAL * H_LAT * 2);
    unsigned short* cb2  = (unsigned short*)carve((size_t)N_TOTAL * H_LAT * 2);
    unsigned short* cb3  = (unsigned short*)carve((size_t)N_TOTAL * H_LAT * 2);
    int*   cnt     = (int*)carve((size_t)CNT_PAD * 4);
    int*   row_ptr = (int*)carve((size_t)CNT_PAD * 4);
    int*   row_ofs = (int*)carve((size_t)CNT_PAD * 4);
    int*   csr_col = (int*)carve((size_t)NNZ_E * 4);
    float* csr_val = (float*)carve((size_t)NNZ_E * 4);

    hipMemsetAsync(cnt, 0, (size_t)CNT_PAD * 4, stream);

    prep_wt_kernel<<<512, 256, 0, stream>>>(W_red, WT);
    gemm1_kernel<<<1172, 256, 0, stream>>>(X, WT, b_red, emb);

    hist_kernel<<<NNZ_E / 256, 256, 0, stream>>>(e_rows, cnt);
    scan_kernel<<<1, 1024, 0, stream>>>(cnt, row_ptr, row_ofs);
    scatter_kernel<<<NNZ_E / 256, 256, 0, stream>>>(e_rows, e_cols, e_vals, row_ofs, csr_col, csr_val);

    spmm_kernel<<<N_TOTAL / 4, 256, 0, stream>>>(emb, cb1, row_ptr, csr_col, csr_val);
    spmm_kernel<<<N_TOTAL / 4, 256, 0, stream>>>(cb1, cb2, row_ptr, csr_col, csr_val);
    spmm_kernel<<<N_TOTAL / 4, 256, 0, stream>>>(cb2, cb3, row_ptr, csr_col, csr_val);

    cls_kernel<<<(N_NODES + 255) / 256, 256, 0, stream>>>(emb, cb1, cb2, cb3, W_cls, b_cls, out);
}

// Round 2
// 2152.996 us; speedup vs baseline: 1.2283x; 1.2283x over previous
//
#include <hip/hip_runtime.h>

#define N_NODES 100000
#define M_HYPER 50000
#define N_TOTAL 150000
#define D_IN    512
#define H_LAT   256
#define N_CLASS 40
#define NNZ_E   4800000
#define CNT_PAD 151552   // 37 * 4096, >= N_TOTAL+1
#define BK      128

typedef float  floatx4 __attribute__((ext_vector_type(4)));
typedef __bf16 bf16x8  __attribute__((ext_vector_type(8)));

__device__ __forceinline__ unsigned short bf16_rne(float f) {
    unsigned u = __float_as_uint(f);
    return (unsigned short)((u + 0x7FFFu + ((u >> 16) & 1u)) >> 16);
}

// ---------------- W_red transpose + bf16 convert: W[512][256] -> WT[256][512] ----------------
__global__ void __launch_bounds__(256) prep_wt_kernel(const float* __restrict__ W,
                                                      unsigned short* __restrict__ WT) {
    int t = blockIdx.x * 256 + threadIdx.x;      // 0 .. 512*256-1
    if (t < D_IN * H_LAT) {
        int k = t >> 8;          // 0..511
        int n = t & 255;         // 0..255
        WT[n * D_IN + k] = bf16_rne(W[t]);
    }
}

// ---------------- GEMM1: emb = X @ W_red + b_red  (LDS-tiled bf16 MFMA) ----------------------
// block = 256 thr (4 waves). Block tile: 64 rows x 256 cols. Wave wv owns cols [wv*64, wv*64+64).
// A (X rows) staged to LDS as bf16, coalesced float4 global loads. B (WT) read from global (L2).
__global__ void __launch_bounds__(256, 3) gemm1_kernel(const float* __restrict__ X,
                                                       const unsigned short* __restrict__ WT,
                                                       const float* __restrict__ brd,
                                                       unsigned short* __restrict__ emb) {
    __shared__ unsigned short As[64][BK + 8];   // +8 shorts pad -> 2-way-free banks
    int tid  = threadIdx.x;
    int wv   = tid >> 6;
    int lane = tid & 63;
    int l16  = lane & 15;
    int quad = lane >> 4;
    int row0 = blockIdx.x * 64;

    floatx4 acc[4][4];
#pragma unroll
    for (int a = 0; a < 4; ++a)
#pragma unroll
        for (int b = 0; b < 4; ++b) acc[a][b] = (floatx4)0.f;

#pragma unroll 1
    for (int k0 = 0; k0 < D_IN; k0 += BK) {
        // stage A: 64 rows x 128 k (fp32 -> bf16). 2048 float4s, 8 per thread.
#pragma unroll
        for (int j = 0; j < 8; ++j) {
            int idx = tid + 256 * j;
            int r = idx >> 5;            // 0..63
            int c = (idx & 31) << 2;     // 0..124
            int gr = min(row0 + r, N_TOTAL - 1);
            float4 v = *(const float4*)(X + (size_t)gr * D_IN + k0 + c);
            ushort4 u;
            u.x = bf16_rne(v.x); u.y = bf16_rne(v.y); u.z = bf16_rne(v.z); u.w = bf16_rne(v.w);
            *(ushort4*)(&As[r][c]) = u;
        }
        __syncthreads();

#pragma unroll
        for (int ks = 0; ks < BK; ks += 32) {
            bf16x8 af[4];
#pragma unroll
            for (int rt = 0; rt < 4; ++rt)
                af[rt] = *(const bf16x8*)(&As[rt * 16 + l16][ks + quad * 8]);
#pragma unroll
            for (int ct = 0; ct < 4; ++ct) {
                int col = wv * 64 + ct * 16 + l16;
                bf16x8 bw = *(const bf16x8*)(WT + (size_t)col * D_IN + k0 + ks + quad * 8);
#pragma unroll
                for (int rt = 0; rt < 4; ++rt)
                    acc[rt][ct] = __builtin_amdgcn_mfma_f32_16x16x32_bf16(af[rt], bw, acc[rt][ct], 0, 0, 0);
            }
        }
        __syncthreads();
    }

    // epilogue: C layout col = l16 (+16*ct), row = quad*4 + r (+16*rt)
#pragma unroll
    for (int ct = 0; ct < 4; ++ct) {
        int col = wv * 64 + ct * 16 + l16;
        float bias = brd[col];
#pragma unroll
        for (int rt = 0; rt < 4; ++rt) {
#pragma unroll
            for (int r = 0; r < 4; ++r) {
                int row = row0 + rt * 16 + quad * 4 + r;
                if (row < N_TOTAL)
                    emb[(size_t)row * H_LAT + col] = bf16_rne(acc[rt][ct][r] + bias);
            }
        }
    }
}

// ---------------- CSR build ----------------
__global__ void __launch_bounds__(256) hist_kernel(const int* __restrict__ rows, int* __restrict__ cnt) {
    int t = blockIdx.x * 256 + threadIdx.x;
    if (t < NNZ_E / 4) {
        int4 r = ((const int4*)rows)[t];
        atomicAdd(&cnt[r.x], 1);
        atomicAdd(&cnt[r.y], 1);
        atomicAdd(&cnt[r.z], 1);
        atomicAdd(&cnt[r.w], 1);
    }
}

// single-block exclusive scan over CNT_PAD padded counters (zeros beyond N_TOTAL).
__global__ void __launch_bounds__(1024) scan_kernel(const int* __restrict__ cnt,
                                                    int* __restrict__ row_ptr,
                                                    int* __restrict__ row_ofs) {
    __shared__ int wsum[16];
    int tid = threadIdx.x;
    int lane = tid & 63, wid = tid >> 6;
    int running = 0;
    for (int base = 0; base < CNT_PAD; base += 4096) {
        int idx = base + tid * 4;
        int4 v = *(const int4*)(cnt + idx);
        int t0 = v.x, t1 = t0 + v.y, t2 = t1 + v.z, t3 = t2 + v.w;
        int tsum = t3;
        int s = tsum;
#pragma unroll
        for (int d = 1; d < 64; d <<= 1) {
            int o = __shfl_up(s, d);
            if (lane >= d) s += o;
        }
        if (lane == 63) wsum[wid] = s;
        __syncthreads();
        if (wid == 0) {
            int ws = (lane < 16) ? wsum[lane] : 0;
#pragma unroll
            for (int d = 1; d < 16; d <<= 1) {
                int o = __shfl_up(ws, d);
                if (lane >= d) ws += o;
            }
            if (lane < 16) wsum[lane] = ws;
        }
        __syncthreads();
        int waveoff = (wid == 0) ? 0 : wsum[wid - 1];
        int total   = wsum[15];
        int eb = running + waveoff + (s - tsum);
        int4 o4 = make_int4(eb, eb + t0, eb + t1, eb + t2);
        *(int4*)(row_ptr + idx) = o4;
        *(int4*)(row_ofs + idx) = o4;
        running += total;
        __syncthreads();
    }
}

__global__ void __launch_bounds__(256) scatter_kernel(const int* __restrict__ rows,
                                                      const int* __restrict__ cols,
                                                      const float* __restrict__ vals,
                                                      int* __restrict__ row_ofs,
                                                      int2* __restrict__ csr_ev) {
    int t = blockIdx.x * 256 + threadIdx.x;
    if (t < NNZ_E / 4) {
        int4 r = ((const int4*)rows)[t];
        int4 c = ((const int4*)cols)[t];
        float4 v = ((const float4*)vals)[t];
        int p0 = atomicAdd(&row_ofs[r.x], 1);
        csr_ev[p0] = make_int2(c.x, __float_as_int(v.x));
        int p1 = atomicAdd(&row_ofs[r.y], 1);
        csr_ev[p1] = make_int2(c.y, __float_as_int(v.y));
        int p2 = atomicAdd(&row_ofs[r.z], 1);
        csr_ev[p2] = make_int2(c.z, __float_as_int(v.z));
        int p3 = atomicAdd(&row_ofs[r.w], 1);
        csr_ev[p3] = make_int2(c.w, __float_as_int(v.w));
    }
}

// ---------------- SpMM: cout[r,:] = sum_e val[e] * cin[col[e],:]  (one wave per row) ----------
__global__ void __launch_bounds__(256) spmm_kernel(const unsigned short* __restrict__ cin,
                                                   unsigned short* __restrict__ cout,
                                                   const int* __restrict__ row_ptr,
                                                   const int2* __restrict__ csr_ev,
                                                   int nrows) {
    int r = (blockIdx.x * 256 + threadIdx.x) >> 6;
    if (r >= nrows) return;
    int lane = threadIdx.x & 63;
    int beg = row_ptr[r], end = row_ptr[r + 1];

    float a0 = 0.f, a1 = 0.f, a2 = 0.f, a3 = 0.f;
    const unsigned short* basep = cin + lane * 4;

    for (int b = beg; b < end; b += 64) {
        int e = b + lane;
        int2 ev = make_int2(0, 0);
        if (e < end) ev = csr_ev[e];
        int n = min(64, end - b);
        int i = 0;
        for (; i + 4 <= n; i += 4) {
            int   c0 = __shfl(ev.x, i);
            int   c1 = __shfl(ev.x, i + 1);
            int   c2 = __shfl(ev.x, i + 2);
            int   c3 = __shfl(ev.x, i + 3);
            float v0 = __uint_as_float((unsigned)__shfl(ev.y, i));
            float v1 = __uint_as_float((unsigned)__shfl(ev.y, i + 1));
            float v2 = __uint_as_float((unsigned)__shfl(ev.y, i + 2));
            float v3 = __uint_as_float((unsigned)__shfl(ev.y, i + 3));
            uint2 g0 = *(const uint2*)(basep + (size_t)c0 * H_LAT);
            uint2 g1 = *(const uint2*)(basep + (size_t)c1 * H_LAT);
            uint2 g2 = *(const uint2*)(basep + (size_t)c2 * H_LAT);
            uint2 g3 = *(const uint2*)(basep + (size_t)c3 * H_LAT);
            a0 = fmaf(v0, __uint_as_float(g0.x << 16),         a0);
            a1 = fmaf(v0, __uint_as_float(g0.x & 0xFFFF0000u), a1);
            a2 = fmaf(v0, __uint_as_float(g0.y << 16),         a2);
            a3 = fmaf(v0, __uint_as_float(g0.y & 0xFFFF0000u), a3);
            a0 = fmaf(v1, __uint_as_float(g1.x << 16),         a0);
            a1 = fmaf(v1, __uint_as_float(g1.x & 0xFFFF0000u), a1);
            a2 = fmaf(v1, __uint_as_float(g1.y << 16),         a2);
            a3 = fmaf(v1, __uint_as_float(g1.y & 0xFFFF0000u), a3);
            a0 = fmaf(v2, __uint_as_float(g2.x << 16),         a0);
            a1 = fmaf(v2, __uint_as_float(g2.x & 0xFFFF0000u), a1);
            a2 = fmaf(v2, __uint_as_float(g2.y << 16),         a2);
            a3 = fmaf(v2, __uint_as_float(g2.y & 0xFFFF0000u), a3);
            a0 = fmaf(v3, __uint_as_float(g3.x << 16),         a0);
            a1 = fmaf(v3, __uint_as_float(g3.x & 0xFFFF0000u), a1);
            a2 = fmaf(v3, __uint_as_float(g3.y << 16),         a2);
            a3 = fmaf(v3, __uint_as_float(g3.y & 0xFFFF0000u), a3);
        }
        for (; i < n; ++i) {
            int   cc = __shfl(ev.x, i);
            float vv = __uint_as_float((unsigned)__shfl(ev.y, i));
            uint2 g = *(const uint2*)(basep + (size_t)cc * H_LAT);
            a0 = fmaf(vv, __uint_as_float(g.x << 16),         a0);
            a1 = fmaf(vv, __uint_as_float(g.x & 0xFFFF0000u), a1);
            a2 = fmaf(vv, __uint_as_float(g.y << 16),         a2);
            a3 = fmaf(vv, __uint_as_float(g.y & 0xFFFF0000u), a3);
        }
    }
    unsigned r01 = (unsigned)bf16_rne(a0) | ((unsigned)bf16_rne(a1) << 16);
    unsigned r23 = (unsigned)bf16_rne(a2) | ((unsigned)bf16_rne(a3) << 16);
    uint2 o; o.x = r01; o.y = r23;
    *(uint2*)(cout + (size_t)r * H_LAT + lane * 4) = o;
}

// ---------------- fused classifier: Z = ((emb+c1+c2+c3)/4) @ W_cls + b_cls; log_softmax -------
__global__ void __launch_bounds__(256) cls_kernel(const unsigned short* __restrict__ emb,
                                                  const unsigned short* __restrict__ c1,
                                                  const unsigned short* __restrict__ c2,
                                                  const unsigned short* __restrict__ c3,
                                                  const float* __restrict__ W,
                                                  const float* __restrict__ bc,
                                                  float* __restrict__ out) {
    __shared__ float Wl[H_LAT * N_CLASS];
    __shared__ float bl[N_CLASS];
    for (int i = threadIdx.x; i < H_LAT * N_CLASS; i += 256) Wl[i] = W[i];
    if (threadIdx.x < N_CLASS) bl[threadIdx.x] = bc[threadIdx.x];
    __syncthreads();

    int r = blockIdx.x * 256 + threadIdx.x;
    if (r >= N_NODES) return;

    float Z[N_CLASS];
#pragma unroll
    for (int c = 0; c < N_CLASS; ++c) Z[c] = bl[c];

    const unsigned short* p0 = emb + (size_t)r * H_LAT;
    const unsigned short* p1 = c1 + (size_t)r * H_LAT;
    const unsigned short* p2 = c2 + (size_t)r * H_LAT;
    const unsigned short* p3 = c3 + (size_t)r * H_LAT;

    for (int f = 0; f < H_LAT; f += 8) {
        uint4 g0 = *(const uint4*)(p0 + f);
        uint4 g1 = *(const uint4*)(p1 + f);
        uint4 g2 = *(const uint4*)(p2 + f);
        uint4 g3 = *(const uint4*)(p3 + f);
        float af[8];
        af[0] = 0.25f * (__uint_as_float(g0.x << 16) + __uint_as_float(g1.x << 16) +
                         __uint_as_float(g2.x << 16) + __uint_as_float(g3.x << 16));
        af[1] = 0.25f * (__uint_as_float(g0.x & 0xFFFF0000u) + __uint_as_float(g1.x & 0xFFFF0000u) +
                         __uint_as_float(g2.x & 0xFFFF0000u) + __uint_as_float(g3.x & 0xFFFF0000u));
        af[2] = 0.25f * (__uint_as_float(g0.y << 16) + __uint_as_float(g1.y << 16) +
                         __uint_as_float(g2.y << 16) + __uint_as_float(g3.y << 16));
        af[3] = 0.25f * (__uint_as_float(g0.y & 0xFFFF0000u) + __uint_as_float(g1.y & 0xFFFF0000u) +
                         __uint_as_float(g2.y & 0xFFFF0000u) + __uint_as_float(g3.y & 0xFFFF0000u));
        af[4] = 0.25f * (__uint_as_float(g0.z << 16) + __uint_as_float(g1.z << 16) +
                         __uint_as_float(g2.z << 16) + __uint_as_float(g3.z << 16));
        af[5] = 0.25f * (__uint_as_float(g0.z & 0xFFFF0000u) + __uint_as_float(g1.z & 0xFFFF0000u) +
                         __uint_as_float(g2.z & 0xFFFF0000u) + __uint_as_float(g3.z & 0xFFFF0000u));
        af[6] = 0.25f * (__uint_as_float(g0.w << 16) + __uint_as_float(g1.w << 16) +
                         __uint_as_float(g2.w << 16) + __uint_as_float(g3.w << 16));
        af[7] = 0.25f * (__uint_as_float(g0.w & 0xFFFF0000u) + __uint_as_float(g1.w & 0xFFFF0000u) +
                         __uint_as_float(g2.w & 0xFFFF0000u) + __uint_as_float(g3.w & 0xFFFF0000u));
#pragma unroll
        for (int j = 0; j < 8; ++j) {
            const float* wrow = &Wl[(f + j) * N_CLASS];
#pragma unroll
            for (int c = 0; c < N_CLASS; ++c) Z[c] = fmaf(af[j], wrow[c], Z[c]);
        }
    }

    float m = Z[0];
#pragma unroll
    for (int c = 1; c < N_CLASS; ++c) m = fmaxf(m, Z[c]);
    float s = 0.f;
#pragma unroll
    for (int c = 0; c < N_CLASS; ++c) s += __expf(Z[c] - m);
    float ls = __logf(s) + m;
#pragma unroll
    for (int c = 0; c < N_CLASS; ++c) out[(size_t)r * N_CLASS + c] = Z[c] - ls;
}

// ---------------- launch ----------------
extern "C" void kernel_launch(void* const* d_in, const int* in_sizes, int n_in,
                              void* d_out, int out_size, void* d_ws, size_t ws_size,
                              hipStream_t stream) {
    const float* X        = (const float*)d_in[0];
    const float* W_red    = (const float*)d_in[1];
    const float* b_red    = (const float*)d_in[2];
    const float* W_cls    = (const float*)d_in[3];
    const float* b_cls    = (const float*)d_in[4];
    const float* e_vals   = (const float*)d_in[5];
    const int*   e_rows   = (const int*)d_in[6];
    const int*   e_cols   = (const int*)d_in[7];
    float* out = (float*)d_out;

    char* p = (char*)d_ws;
    auto carve = [&](size_t bytes) -> void* {
        void* r = (void*)p;
        p += (bytes + 255) & ~(size_t)255;
        return r;
    };
    unsigned short* WT   = (unsigned short*)carve((size_t)H_LAT * D_IN * 2);
    unsigned short* emb  = (unsigned short*)carve((size_t)N_TOTAL * H_LAT * 2);
    unsigned short* cb1  = (unsigned short*)carve((size_t)N_TOTAL * H_LAT * 2);
    unsigned short* cb2  = (unsigned short*)carve((size_t)N_TOTAL * H_LAT * 2);
    unsigned short* cb3  = (unsigned short*)carve((size_t)N_TOTAL * H_LAT * 2);
    int*   cnt     = (int*)carve((size_t)CNT_PAD * 4);
    int*   row_ptr = (int*)carve((size_t)CNT_PAD * 4);
    int*   row_ofs = (int*)carve((size_t)CNT_PAD * 4);
    int2*  csr_ev  = (int2*)carve((size_t)NNZ_E * 8);

    hipMemsetAsync(cnt, 0, (size_t)CNT_PAD * 4, stream);

    prep_wt_kernel<<<512, 256, 0, stream>>>(W_red, WT);
    gemm1_kernel<<<(N_TOTAL + 63) / 64, 256, 0, stream>>>(X, WT, b_red, emb);

    hist_kernel<<<(NNZ_E / 4 + 255) / 256, 256, 0, stream>>>(e_rows, cnt);
    scan_kernel<<<1, 1024, 0, stream>>>(cnt, row_ptr, row_ofs);
    scatter_kernel<<<(NNZ_E / 4 + 255) / 256, 256, 0, stream>>>(e_rows, e_cols, e_vals, row_ofs, csr_ev);

    spmm_kernel<<<N_TOTAL / 4, 256, 0, stream>>>(emb, cb1, row_ptr, csr_ev, N_TOTAL);
    spmm_kernel<<<N_TOTAL / 4, 256, 0, stream>>>(cb1, cb2, row_ptr, csr_ev, N_TOTAL);
    spmm_kernel<<<N_NODES / 4, 256, 0, stream>>>(cb2, cb3, row_ptr, csr_ev, N_NODES);

    cls_kernel<<<(N_NODES + 255) / 256, 256, 0, stream>>>(emb, cb1, cb2, cb3, W_cls, b_cls, out);
}

// Round 3
// 2043.011 us; speedup vs baseline: 1.2945x; 1.0538x over previous
//
#include <hip/hip_runtime.h>

#define N_NODES 100000
#define M_HYPER 50000
#define N_TOTAL 150000
#define D_IN    512
#define H_LAT   256
#define N_CLASS 40
#define NNZ_E   4800000
#define CNT_PAD 151552   // 37 * 4096, >= N_TOTAL+1
#define BK      128
#define BROWS   256
#define NB      ((N_TOTAL + BROWS - 1) / BROWS)   // 586 buckets
#define CH      4096

typedef float  floatx4 __attribute__((ext_vector_type(4)));
typedef __bf16 bf16x8  __attribute__((ext_vector_type(8)));

__device__ __forceinline__ unsigned short bf16_rne(float f) {
    unsigned u = __float_as_uint(f);
    return (unsigned short)((u + 0x7FFFu + ((u >> 16) & 1u)) >> 16);
}
__device__ __forceinline__ float blo(unsigned w) { return __uint_as_float(w << 16); }
__device__ __forceinline__ float bhi(unsigned w) { return __uint_as_float(w & 0xFFFF0000u); }

// ---------------- W_red transpose + bf16 convert: W[512][256] -> WT[256][512] ----------------
__global__ void __launch_bounds__(256) prep_wt_kernel(const float* __restrict__ W,
                                                      unsigned short* __restrict__ WT) {
    int t = blockIdx.x * 256 + threadIdx.x;
    if (t < D_IN * H_LAT) {
        int k = t >> 8;
        int n = t & 255;
        WT[n * D_IN + k] = bf16_rne(W[t]);
    }
}

// ---------------- GEMM1: emb = X @ W_red + b_red  (LDS-tiled bf16 MFMA) ----------------------
__global__ void __launch_bounds__(256, 3) gemm1_kernel(const float* __restrict__ X,
                                                       const unsigned short* __restrict__ WT,
                                                       const float* __restrict__ brd,
                                                       unsigned short* __restrict__ emb) {
    __shared__ unsigned short As[64][BK + 8];
    int tid  = threadIdx.x;
    int wv   = tid >> 6;
    int lane = tid & 63;
    int l16  = lane & 15;
    int quad = lane >> 4;
    int row0 = blockIdx.x * 64;

    floatx4 acc[4][4];
#pragma unroll
    for (int a = 0; a < 4; ++a)
#pragma unroll
        for (int b = 0; b < 4; ++b) acc[a][b] = (floatx4)0.f;

#pragma unroll 1
    for (int k0 = 0; k0 < D_IN; k0 += BK) {
#pragma unroll
        for (int j = 0; j < 8; ++j) {
            int idx = tid + 256 * j;
            int r = idx >> 5;
            int c = (idx & 31) << 2;
            int gr = min(row0 + r, N_TOTAL - 1);
            float4 v = *(const float4*)(X + (size_t)gr * D_IN + k0 + c);
            ushort4 u;
            u.x = bf16_rne(v.x); u.y = bf16_rne(v.y); u.z = bf16_rne(v.z); u.w = bf16_rne(v.w);
            *(ushort4*)(&As[r][c]) = u;
        }
        __syncthreads();

#pragma unroll
        for (int ks = 0; ks < BK; ks += 32) {
            bf16x8 af[4];
#pragma unroll
            for (int rt = 0; rt < 4; ++rt)
                af[rt] = *(const bf16x8*)(&As[rt * 16 + l16][ks + quad * 8]);
#pragma unroll
            for (int ct = 0; ct < 4; ++ct) {
                int col = wv * 64 + ct * 16 + l16;
                bf16x8 bw = *(const bf16x8*)(WT + (size_t)col * D_IN + k0 + ks + quad * 8);
#pragma unroll
                for (int rt = 0; rt < 4; ++rt)
                    acc[rt][ct] = __builtin_amdgcn_mfma_f32_16x16x32_bf16(af[rt], bw, acc[rt][ct], 0, 0, 0);
            }
        }
        __syncthreads();
    }

#pragma unroll
    for (int ct = 0; ct < 4; ++ct) {
        int col = wv * 64 + ct * 16 + l16;
        float bias = brd[col];
#pragma unroll
        for (int rt = 0; rt < 4; ++rt) {
#pragma unroll
            for (int r = 0; r < 4; ++r) {
                int row = row0 + rt * 16 + quad * 4 + r;
                if (row < N_TOTAL)
                    emb[(size_t)row * H_LAT + col] = bf16_rne(acc[rt][ct][r] + bias);
            }
        }
    }
}

// ---------------- CSR build ----------------
__global__ void __launch_bounds__(256) hist_kernel(const int* __restrict__ rows, int* __restrict__ cnt) {
    int t = blockIdx.x * 256 + threadIdx.x;
    if (t < NNZ_E / 4) {
        int4 r = ((const int4*)rows)[t];
        atomicAdd(&cnt[r.x], 1);
        atomicAdd(&cnt[r.y], 1);
        atomicAdd(&cnt[r.z], 1);
        atomicAdd(&cnt[r.w], 1);
    }
}

__global__ void __launch_bounds__(1024) scan_kernel(const int* __restrict__ cnt,
                                                    int* __restrict__ row_ptr,
                                                    int* __restrict__ row_ofs) {
    __shared__ int wsum[16];
    int tid = threadIdx.x;
    int lane = tid & 63, wid = tid >> 6;
    int running = 0;
    for (int base = 0; base < CNT_PAD; base += 4096) {
        int idx = base + tid * 4;
        int4 v = *(const int4*)(cnt + idx);
        int t0 = v.x, t1 = t0 + v.y, t2 = t1 + v.z, t3 = t2 + v.w;
        int tsum = t3;
        int s = tsum;
#pragma unroll
        for (int d = 1; d < 64; d <<= 1) {
            int o = __shfl_up(s, d);
            if (lane >= d) s += o;
        }
        if (lane == 63) wsum[wid] = s;
        __syncthreads();
        if (wid == 0) {
            int ws = (lane < 16) ? wsum[lane] : 0;
#pragma unroll
            for (int d = 1; d < 16; d <<= 1) {
                int o = __shfl_up(ws, d);
                if (lane >= d) ws += o;
            }
            if (lane < 16) wsum[lane] = ws;
        }
        __syncthreads();
        int waveoff = (wid == 0) ? 0 : wsum[wid - 1];
        int total   = wsum[15];
        int eb = running + waveoff + (s - tsum);
        int4 o4 = make_int4(eb, eb + t0, eb + t1, eb + t2);
        *(int4*)(row_ptr + idx) = o4;
        *(int4*)(row_ofs + idx) = o4;
        running += total;
        __syncthreads();
    }
}

// bucket_fill[b] = start of bucket b's span in CSR/binned order
__global__ void __launch_bounds__(256) initfill_kernel(const int* __restrict__ row_ptr,
                                                       int* __restrict__ bucket_fill) {
    int b = blockIdx.x * 256 + threadIdx.x;
    if (b < NB) bucket_fill[b] = row_ptr[min(b * BROWS, N_TOTAL)];
}

// Phase A: bin edges into 586 coarse buckets (contiguous runs per block-bin -> compact writes)
__global__ void __launch_bounds__(256) binA_kernel(const int* __restrict__ rows,
                                                   const int* __restrict__ cols,
                                                   const float* __restrict__ vals,
                                                   int* __restrict__ bucket_fill,
                                                   int2* __restrict__ binned) {
    __shared__ int hist[NB];
    int tid = threadIdx.x;
    long base = (long)blockIdx.x * CH;
    for (int i = tid; i < NB; i += 256) hist[i] = 0;
    __syncthreads();

    int mybkt[16];
    int myrl[16];
#pragma unroll
    for (int j = 0; j < 16; ++j) {
        long e = base + j * 256 + tid;
        int b = -1, rl = 0;
        if (e < NNZ_E) {
            int r = rows[e];
            b = r >> 8;
            rl = r & 255;
            atomicAdd(&hist[b], 1);
        }
        mybkt[j] = b; myrl[j] = rl;
    }
    __syncthreads();
    for (int b = tid; b < NB; b += 256) {
        int c = hist[b];
        int g = 0;
        if (c > 0) g = atomicAdd(&bucket_fill[b], c);
        hist[b] = g;   // becomes the global write cursor for this chunk's bin
    }
    __syncthreads();
#pragma unroll
    for (int j = 0; j < 16; ++j) {
        long e = base + j * 256 + tid;
        if (e < NNZ_E) {
            int b = mybkt[j];
            int pos = atomicAdd(&hist[b], 1);
            int c = cols[e];
            float v = vals[e];
            binned[pos] = make_int2(c | (myrl[j] << 18), __float_as_int(v));
        }
    }
}

// Phase B: fine scatter within one bucket per block (random writes confined to ~64 KB, L2-hot)
__global__ void __launch_bounds__(256) binB_kernel(const int* __restrict__ row_ptr,
                                                   const int2* __restrict__ binned,
                                                   int* __restrict__ row_ofs,
                                                   int2* __restrict__ csr_ev) {
    int b = blockIdx.x;
    int s = row_ptr[b * BROWS];
    int e = row_ptr[min((b + 1) * BROWS, N_TOTAL)];
    int rbase = b << 8;
    for (int t = s + (int)threadIdx.x; t < e; t += 256) {
        int2 w = binned[t];
        int rl  = ((unsigned)w.x) >> 18;
        int col = w.x & 0x3FFFF;
        int p = atomicAdd(&row_ofs[rbase + rl], 1);
        csr_ev[p] = make_int2(col, w.y);
    }
}

// ---------------- SpMM: cout[r,:] = sum_e val[e] * cin[col[e],:] --------------------------------
// one wave per row; half-waves (32 lanes) each gather a full 256-bf16 row via one uint4 load,
// so each memory instruction fetches TWO edges' rows (1 KB). 4 gathers kept in flight.
__global__ void __launch_bounds__(256) spmm_kernel(const unsigned short* __restrict__ cin,
                                                   unsigned short* __restrict__ cout,
                                                   const int* __restrict__ row_ptr,
                                                   const int2* __restrict__ csr_ev,
                                                   int nrows) {
    int r = (blockIdx.x * 256 + threadIdx.x) >> 6;
    if (r >= nrows) return;
    int lane = threadIdx.x & 63;
    int half = lane >> 5;
    int l32  = lane & 31;
    int beg = row_ptr[r], end = row_ptr[r + 1];

    float a[8];
#pragma unroll
    for (int j = 0; j < 8; ++j) a[j] = 0.f;
    const unsigned short* basep = cin + l32 * 8;

    for (int b = beg; b < end; b += 64) {
        int e = b + lane;
        int2 ev = (e < end) ? csr_ev[e] : make_int2(0, 0);  // col 0 / val 0 -> harmless
        int n = min(64, end - b);
        for (int i = 0; i < n; i += 8) {
            int cc[4]; float vv[4];
#pragma unroll
            for (int u = 0; u < 4; ++u) {
                int src = i + 2 * u + half;
                cc[u] = __shfl(ev.x, src);
                vv[u] = __uint_as_float((unsigned)__shfl(ev.y, src));
            }
            uint4 g[4];
#pragma unroll
            for (int u = 0; u < 4; ++u)
                g[u] = *(const uint4*)(basep + (size_t)cc[u] * H_LAT);
#pragma unroll
            for (int u = 0; u < 4; ++u) {
                a[0] = fmaf(vv[u], blo(g[u].x), a[0]);
                a[1] = fmaf(vv[u], bhi(g[u].x), a[1]);
                a[2] = fmaf(vv[u], blo(g[u].y), a[2]);
                a[3] = fmaf(vv[u], bhi(g[u].y), a[3]);
                a[4] = fmaf(vv[u], blo(g[u].z), a[4]);
                a[5] = fmaf(vv[u], bhi(g[u].z), a[5]);
                a[6] = fmaf(vv[u], blo(g[u].w), a[6]);
                a[7] = fmaf(vv[u], bhi(g[u].w), a[7]);
            }
        }
    }
#pragma unroll
    for (int j = 0; j < 8; ++j) a[j] += __shfl_xor(a[j], 32);

    if (half == 0) {
        uint4 o;
        o.x = (unsigned)bf16_rne(a[0]) | ((unsigned)bf16_rne(a[1]) << 16);
        o.y = (unsigned)bf16_rne(a[2]) | ((unsigned)bf16_rne(a[3]) << 16);
        o.z = (unsigned)bf16_rne(a[4]) | ((unsigned)bf16_rne(a[5]) << 16);
        o.w = (unsigned)bf16_rne(a[6]) | ((unsigned)bf16_rne(a[7]) << 16);
        *(uint4*)(cout + (size_t)r * H_LAT + l32 * 8) = o;
    }
}

// ---------------- fused classifier: Z = ((emb+c1+c2+c3)/4) @ W_cls + b_cls; log_softmax -------
__global__ void __launch_bounds__(256) cls_kernel(const unsigned short* __restrict__ emb,
                                                  const unsigned short* __restrict__ c1,
                                                  const unsigned short* __restrict__ c2,
                                                  const unsigned short* __restrict__ c3,
                                                  const float* __restrict__ W,
                                                  const float* __restrict__ bc,
                                                  float* __restrict__ out) {
    __shared__ float Wl[H_LAT * N_CLASS];
    __shared__ float bl[N_CLASS];
    for (int i = threadIdx.x; i < H_LAT * N_CLASS; i += 256) Wl[i] = W[i];
    if (threadIdx.x < N_CLASS) bl[threadIdx.x] = bc[threadIdx.x];
    __syncthreads();

    int r = blockIdx.x * 256 + threadIdx.x;
    if (r >= N_NODES) return;

    float Z[N_CLASS];
#pragma unroll
    for (int c = 0; c < N_CLASS; ++c) Z[c] = bl[c];

    const unsigned short* p0 = emb + (size_t)r * H_LAT;
    const unsigned short* p1 = c1 + (size_t)r * H_LAT;
    const unsigned short* p2 = c2 + (size_t)r * H_LAT;
    const unsigned short* p3 = c3 + (size_t)r * H_LAT;

    for (int f = 0; f < H_LAT; f += 8) {
        uint4 g0 = *(const uint4*)(p0 + f);
        uint4 g1 = *(const uint4*)(p1 + f);
        uint4 g2 = *(const uint4*)(p2 + f);
        uint4 g3 = *(const uint4*)(p3 + f);
        float af[8];
        af[0] = 0.25f * (blo(g0.x) + blo(g1.x) + blo(g2.x) + blo(g3.x));
        af[1] = 0.25f * (bhi(g0.x) + bhi(g1.x) + bhi(g2.x) + bhi(g3.x));
        af[2] = 0.25f * (blo(g0.y) + blo(g1.y) + blo(g2.y) + blo(g3.y));
        af[3] = 0.25f * (bhi(g0.y) + bhi(g1.y) + bhi(g2.y) + bhi(g3.y));
        af[4] = 0.25f * (blo(g0.z) + blo(g1.z) + blo(g2.z) + blo(g3.z));
        af[5] = 0.25f * (bhi(g0.z) + bhi(g1.z) + bhi(g2.z) + bhi(g3.z));
        af[6] = 0.25f * (blo(g0.w) + blo(g1.w) + blo(g2.w) + blo(g3.w));
        af[7] = 0.25f * (bhi(g0.w) + bhi(g1.w) + bhi(g2.w) + bhi(g3.w));
#pragma unroll
        for (int j = 0; j < 8; ++j) {
            const float* wrow = &Wl[(f + j) * N_CLASS];
#pragma unroll
            for (int c = 0; c < N_CLASS; ++c) Z[c] = fmaf(af[j], wrow[c], Z[c]);
        }
    }

    float m = Z[0];
#pragma unroll
    for (int c = 1; c < N_CLASS; ++c) m = fmaxf(m, Z[c]);
    float s = 0.f;
#pragma unroll
    for (int c = 0; c < N_CLASS; ++c) s += __expf(Z[c] - m);
    float ls = __logf(s) + m;
#pragma unroll
    for (int c = 0; c < N_CLASS; ++c) out[(size_t)r * N_CLASS + c] = Z[c] - ls;
}

// ---------------- launch ----------------
extern "C" void kernel_launch(void* const* d_in, const int* in_sizes, int n_in,
                              void* d_out, int out_size, void* d_ws, size_t ws_size,
                              hipStream_t stream) {
    const float* X        = (const float*)d_in[0];
    const float* W_red    = (const float*)d_in[1];
    const float* b_red    = (const float*)d_in[2];
    const float* W_cls    = (const float*)d_in[3];
    const float* b_cls    = (const float*)d_in[4];
    const float* e_vals   = (const float*)d_in[5];
    const int*   e_rows   = (const int*)d_in[6];
    const int*   e_cols   = (const int*)d_in[7];
    float* out = (float*)d_out;

    char* p = (char*)d_ws;
    auto carve = [&](size_t bytes) -> void* {
        void* r = (void*)p;
        p += (bytes + 255) & ~(size_t)255;
        return r;
    };
    unsigned short* WT   = (unsigned short*)carve((size_t)H_LAT * D_IN * 2);
    unsigned short* emb  = (unsigned short*)carve((size_t)N_TOTAL * H_LAT * 2);
    unsigned short* cb1  = (unsigned short*)carve((size_t)N_TOTAL * H_LAT * 2);
    unsigned short* cb2  = (unsigned short*)carve((size_t)N_TOTAL * H_LAT * 2);
    unsigned short* cb3  = (unsigned short*)carve((size_t)N_TOTAL * H_LAT * 2);
    int*   cnt         = (int*)carve((size_t)CNT_PAD * 4);
    int*   row_ptr     = (int*)carve((size_t)CNT_PAD * 4);
    int*   row_ofs     = (int*)carve((size_t)CNT_PAD * 4);
    int*   bucket_fill = (int*)carve((size_t)NB * 4);
    int2*  csr_ev      = (int2*)carve((size_t)NNZ_E * 8);
    int2*  binned      = (int2*)cb3;   // alias: dead before spmm layer 3 writes cb3

    hipMemsetAsync(cnt, 0, (size_t)CNT_PAD * 4, stream);

    prep_wt_kernel<<<512, 256, 0, stream>>>(W_red, WT);
    gemm1_kernel<<<(N_TOTAL + 63) / 64, 256, 0, stream>>>(X, WT, b_red, emb);

    hist_kernel<<<(NNZ_E / 4 + 255) / 256, 256, 0, stream>>>(e_rows, cnt);
    scan_kernel<<<1, 1024, 0, stream>>>(cnt, row_ptr, row_ofs);
    initfill_kernel<<<(NB + 255) / 256, 256, 0, stream>>>(row_ptr, bucket_fill);
    binA_kernel<<<(NNZ_E + CH - 1) / CH, 256, 0, stream>>>(e_rows, e_cols, e_vals, bucket_fill, binned);
    binB_kernel<<<NB, 256, 0, stream>>>(row_ptr, binned, row_ofs, csr_ev);

    spmm_kernel<<<N_TOTAL / 4, 256, 0, stream>>>(emb, cb1, row_ptr, csr_ev, N_TOTAL);
    spmm_kernel<<<N_TOTAL / 4, 256, 0, stream>>>(cb1, cb2, row_ptr, csr_ev, N_TOTAL);
    spmm_kernel<<<N_NODES / 4, 256, 0, stream>>>(cb2, cb3, row_ptr, csr_ev, N_NODES);

    cls_kernel<<<(N_NODES + 255) / 256, 256, 0, stream>>>(emb, cb1, cb2, cb3, W_cls, b_cls, out);
}

// Round 4
// 1591.582 us; speedup vs baseline: 1.6616x; 1.2836x over previous
//
#include <hip/hip_runtime.h>

#define N_NODES 100000
#define M_HYPER 50000
#define N_TOTAL 150000
#define D_IN    512
#define H_LAT   256
#define N_CLASS 40
#define NNZ_E   4800000
#define CNT_PAD 151552   // 37 * 4096, >= N_TOTAL+1
#define BK      128
#define BROWS   256
#define NB      ((N_TOTAL + BROWS - 1) / BROWS)   // 586 buckets
#define CH      4096

// layer scales: emb8 = 16*emb; each spmm stores 8*a (a already carries input scale)
// => c1_8 = 128*c1, c2_8 = 1024*c2, c3_8 = 8192*c3
#define S_EMB   16.0f
#define SP_OUT  8.0f
#define INV1    (1.0f / 128.0f)
#define INV2    (1.0f / 1024.0f)
#define INV3    (1.0f / 8192.0f)

typedef float  floatx4 __attribute__((ext_vector_type(4)));
typedef float  floatx2 __attribute__((ext_vector_type(2)));
typedef __bf16 bf16x8  __attribute__((ext_vector_type(8)));

__device__ __forceinline__ unsigned short bf16_rne(float f) {
    unsigned u = __float_as_uint(f);
    return (unsigned short)((u + 0x7FFFu + ((u >> 16) & 1u)) >> 16);
}
__device__ __forceinline__ float blo(unsigned w) { return __uint_as_float(w << 16); }
__device__ __forceinline__ float bhi(unsigned w) { return __uint_as_float(w & 0xFFFF0000u); }

__device__ __forceinline__ unsigned pack4fp8(float f0, float f1, float f2, float f3) {
    int d = __builtin_amdgcn_cvt_pk_fp8_f32(f0, f1, 0, false);
    d = __builtin_amdgcn_cvt_pk_fp8_f32(f2, f3, d, true);
    return (unsigned)d;
}

// ---------------- W_red transpose + bf16 convert: W[512][256] -> WT[256][512] ----------------
__global__ void __launch_bounds__(256) prep_wt_kernel(const float* __restrict__ W,
                                                      unsigned short* __restrict__ WT) {
    int t = blockIdx.x * 256 + threadIdx.x;
    if (t < D_IN * H_LAT) {
        int k = t >> 8;
        int n = t & 255;
        WT[n * D_IN + k] = bf16_rne(W[t]);
    }
}

// ---------------- GEMM1: emb = X @ W_red + b_red  (LDS-tiled bf16 MFMA) ----------------------
__global__ void __launch_bounds__(256, 3) gemm1_kernel(const float* __restrict__ X,
                                                       const unsigned short* __restrict__ WT,
                                                       const float* __restrict__ brd,
                                                       unsigned short* __restrict__ emb) {
    __shared__ unsigned short As[64][BK + 8];
    int tid  = threadIdx.x;
    int wv   = tid >> 6;
    int lane = tid & 63;
    int l16  = lane & 15;
    int quad = lane >> 4;
    int row0 = blockIdx.x * 64;

    floatx4 acc[4][4];
#pragma unroll
    for (int a = 0; a < 4; ++a)
#pragma unroll
        for (int b = 0; b < 4; ++b) acc[a][b] = (floatx4)0.f;

#pragma unroll 1
    for (int k0 = 0; k0 < D_IN; k0 += BK) {
#pragma unroll
        for (int j = 0; j < 8; ++j) {
            int idx = tid + 256 * j;
            int r = idx >> 5;
            int c = (idx & 31) << 2;
            int gr = min(row0 + r, N_TOTAL - 1);
            float4 v = *(const float4*)(X + (size_t)gr * D_IN + k0 + c);
            ushort4 u;
            u.x = bf16_rne(v.x); u.y = bf16_rne(v.y); u.z = bf16_rne(v.z); u.w = bf16_rne(v.w);
            *(ushort4*)(&As[r][c]) = u;
        }
        __syncthreads();

#pragma unroll
        for (int ks = 0; ks < BK; ks += 32) {
            bf16x8 af[4];
#pragma unroll
            for (int rt = 0; rt < 4; ++rt)
                af[rt] = *(const bf16x8*)(&As[rt * 16 + l16][ks + quad * 8]);
#pragma unroll
            for (int ct = 0; ct < 4; ++ct) {
                int col = wv * 64 + ct * 16 + l16;
                bf16x8 bw = *(const bf16x8*)(WT + (size_t)col * D_IN + k0 + ks + quad * 8);
#pragma unroll
                for (int rt = 0; rt < 4; ++rt)
                    acc[rt][ct] = __builtin_amdgcn_mfma_f32_16x16x32_bf16(af[rt], bw, acc[rt][ct], 0, 0, 0);
            }
        }
        __syncthreads();
    }

#pragma unroll
    for (int ct = 0; ct < 4; ++ct) {
        int col = wv * 64 + ct * 16 + l16;
        float bias = brd[col];
#pragma unroll
        for (int rt = 0; rt < 4; ++rt) {
#pragma unroll
            for (int r = 0; r < 4; ++r) {
                int row = row0 + rt * 16 + quad * 4 + r;
                if (row < N_TOTAL)
                    emb[(size_t)row * H_LAT + col] = bf16_rne(acc[rt][ct][r] + bias);
            }
        }
    }
}

// ---------------- emb (bf16) -> emb8 (fp8 e4m3, x16) -----------------------------------------
__global__ void __launch_bounds__(256) conv8_kernel(const unsigned short* __restrict__ emb,
                                                    unsigned char* __restrict__ emb8) {
    int t = blockIdx.x * 256 + threadIdx.x;     // handles 8 elements
    if (t < N_TOTAL * H_LAT / 8) {
        uint4 g = ((const uint4*)emb)[t];
        uint2 o;
        o.x = pack4fp8(S_EMB * blo(g.x), S_EMB * bhi(g.x), S_EMB * blo(g.y), S_EMB * bhi(g.y));
        o.y = pack4fp8(S_EMB * blo(g.z), S_EMB * bhi(g.z), S_EMB * blo(g.w), S_EMB * bhi(g.w));
        ((uint2*)emb8)[t] = o;
    }
}

// ---------------- CSR build ----------------
__global__ void __launch_bounds__(256) hist_kernel(const int* __restrict__ rows, int* __restrict__ cnt) {
    int t = blockIdx.x * 256 + threadIdx.x;
    if (t < NNZ_E / 4) {
        int4 r = ((const int4*)rows)[t];
        atomicAdd(&cnt[r.x], 1);
        atomicAdd(&cnt[r.y], 1);
        atomicAdd(&cnt[r.z], 1);
        atomicAdd(&cnt[r.w], 1);
    }
}

__global__ void __launch_bounds__(1024) scan_kernel(const int* __restrict__ cnt,
                                                    int* __restrict__ row_ptr,
                                                    int* __restrict__ row_ofs) {
    __shared__ int wsum[16];
    int tid = threadIdx.x;
    int lane = tid & 63, wid = tid >> 6;
    int running = 0;
    for (int base = 0; base < CNT_PAD; base += 4096) {
        int idx = base + tid * 4;
        int4 v = *(const int4*)(cnt + idx);
        int t0 = v.x, t1 = t0 + v.y, t2 = t1 + v.z, t3 = t2 + v.w;
        int tsum = t3;
        int s = tsum;
#pragma unroll
        for (int d = 1; d < 64; d <<= 1) {
            int o = __shfl_up(s, d);
            if (lane >= d) s += o;
        }
        if (lane == 63) wsum[wid] = s;
        __syncthreads();
        if (wid == 0) {
            int ws = (lane < 16) ? wsum[lane] : 0;
#pragma unroll
            for (int d = 1; d < 16; d <<= 1) {
                int o = __shfl_up(ws, d);
                if (lane >= d) ws += o;
            }
            if (lane < 16) wsum[lane] = ws;
        }
        __syncthreads();
        int waveoff = (wid == 0) ? 0 : wsum[wid - 1];
        int total   = wsum[15];
        int eb = running + waveoff + (s - tsum);
        int4 o4 = make_int4(eb, eb + t0, eb + t1, eb + t2);
        *(int4*)(row_ptr + idx) = o4;
        *(int4*)(row_ofs + idx) = o4;
        running += total;
        __syncthreads();
    }
}

__global__ void __launch_bounds__(256) initfill_kernel(const int* __restrict__ row_ptr,
                                                       int* __restrict__ bucket_fill) {
    int b = blockIdx.x * 256 + threadIdx.x;
    if (b < NB) bucket_fill[b] = row_ptr[min(b * BROWS, N_TOTAL)];
}

// Phase A: bin edges into 586 coarse buckets (contiguous runs per block-bin -> compact writes)
__global__ void __launch_bounds__(256) binA_kernel(const int* __restrict__ rows,
                                                   const int* __restrict__ cols,
                                                   const float* __restrict__ vals,
                                                   int* __restrict__ bucket_fill,
                                                   int2* __restrict__ binned) {
    __shared__ int hist[NB];
    int tid = threadIdx.x;
    long base = (long)blockIdx.x * CH;
    for (int i = tid; i < NB; i += 256) hist[i] = 0;
    __syncthreads();

    int mybkt[16];
    int myrl[16];
#pragma unroll
    for (int j = 0; j < 16; ++j) {
        long e = base + j * 256 + tid;
        int b = -1, rl = 0;
        if (e < NNZ_E) {
            int r = rows[e];
            b = r >> 8;
            rl = r & 255;
            atomicAdd(&hist[b], 1);
        }
        mybkt[j] = b; myrl[j] = rl;
    }
    __syncthreads();
    for (int b = tid; b < NB; b += 256) {
        int c = hist[b];
        int g = 0;
        if (c > 0) g = atomicAdd(&bucket_fill[b], c);
        hist[b] = g;
    }
    __syncthreads();
#pragma unroll
    for (int j = 0; j < 16; ++j) {
        long e = base + j * 256 + tid;
        if (e < NNZ_E) {
            int b = mybkt[j];
            int pos = atomicAdd(&hist[b], 1);
            int c = cols[e];
            float v = vals[e];
            binned[pos] = make_int2(c | (myrl[j] << 18), __float_as_int(v));
        }
    }
}

// Phase B: fine scatter within one bucket per block (random writes confined to ~64 KB, L2-hot)
__global__ void __launch_bounds__(256) binB_kernel(const int* __restrict__ row_ptr,
                                                   const int2* __restrict__ binned,
                                                   int* __restrict__ row_ofs,
                                                   int2* __restrict__ csr_ev) {
    int b = blockIdx.x;
    int s = row_ptr[b * BROWS];
    int e = row_ptr[min((b + 1) * BROWS, N_TOTAL)];
    int rbase = b << 8;
    for (int t = s + (int)threadIdx.x; t < e; t += 256) {
        int2 w = binned[t];
        int rl  = ((unsigned)w.x) >> 18;
        int col = w.x & 0x3FFFF;
        int p = atomicAdd(&row_ofs[rbase + rl], 1);
        csr_ev[p] = make_int2(col, w.y);
    }
}

// ---------------- SpMM (fp8): cout8[r,:] = SP_OUT * sum_e val[e] * cin8[col[e],:] --------------
// one wave per row; quarter-waves (16 lanes x 16 B) each gather a full 256-fp8 row in ONE uint4
// load -> 4 edges per wave memory instruction, 4 gathers in flight. fp32 accumulate.
__global__ void __launch_bounds__(256) spmm8_kernel(const unsigned char* __restrict__ cin8,
                                                    unsigned char* __restrict__ cout8,
                                                    const int* __restrict__ row_ptr,
                                                    const int2* __restrict__ csr_ev,
                                                    int nrows) {
    int r = (blockIdx.x * 256 + threadIdx.x) >> 6;
    if (r >= nrows) return;
    int lane = threadIdx.x & 63;
    int q   = lane >> 4;
    int l16 = lane & 15;
    int beg = row_ptr[r], end = row_ptr[r + 1];

    float a[16];
#pragma unroll
    for (int j = 0; j < 16; ++j) a[j] = 0.f;
    const unsigned char* basep = cin8 + l16 * 16;

    for (int b = beg; b < end; b += 64) {
        int e = b + lane;
        int2 ev = (e < end) ? csr_ev[e] : make_int2(0, 0);  // col 0 / val 0 -> harmless
        int n = min(64, end - b);
        for (int i = 0; i < n; i += 16) {
            int cc[4]; float vv[4]; uint4 g[4];
#pragma unroll
            for (int u = 0; u < 4; ++u) {
                int src = i + 4 * u + q;
                cc[u] = __shfl(ev.x, src);
                vv[u] = __uint_as_float((unsigned)__shfl(ev.y, src));
            }
#pragma unroll
            for (int u = 0; u < 4; ++u) {
                if (i + 4 * u < n) g[u] = *(const uint4*)(basep + (size_t)cc[u] * H_LAT);
                else               g[u] = make_uint4(0, 0, 0, 0);
            }
#pragma unroll
            for (int u = 0; u < 4; ++u) {
                floatx2 p;
                p = __builtin_amdgcn_cvt_pk_f32_fp8(g[u].x, false); a[0]  = fmaf(vv[u], p[0], a[0]);  a[1]  = fmaf(vv[u], p[1], a[1]);
                p = __builtin_amdgcn_cvt_pk_f32_fp8(g[u].x, true);  a[2]  = fmaf(vv[u], p[0], a[2]);  a[3]  = fmaf(vv[u], p[1], a[3]);
                p = __builtin_amdgcn_cvt_pk_f32_fp8(g[u].y, false); a[4]  = fmaf(vv[u], p[0], a[4]);  a[5]  = fmaf(vv[u], p[1], a[5]);
                p = __builtin_amdgcn_cvt_pk_f32_fp8(g[u].y, true);  a[6]  = fmaf(vv[u], p[0], a[6]);  a[7]  = fmaf(vv[u], p[1], a[7]);
                p = __builtin_amdgcn_cvt_pk_f32_fp8(g[u].z, false); a[8]  = fmaf(vv[u], p[0], a[8]);  a[9]  = fmaf(vv[u], p[1], a[9]);
                p = __builtin_amdgcn_cvt_pk_f32_fp8(g[u].z, true);  a[10] = fmaf(vv[u], p[0], a[10]); a[11] = fmaf(vv[u], p[1], a[11]);
                p = __builtin_amdgcn_cvt_pk_f32_fp8(g[u].w, false); a[12] = fmaf(vv[u], p[0], a[12]); a[13] = fmaf(vv[u], p[1], a[13]);
                p = __builtin_amdgcn_cvt_pk_f32_fp8(g[u].w, true);  a[14] = fmaf(vv[u], p[0], a[14]); a[15] = fmaf(vv[u], p[1], a[15]);
            }
        }
    }
#pragma unroll
    for (int j = 0; j < 16; ++j) {
        a[j] += __shfl_xor(a[j], 16);
        a[j] += __shfl_xor(a[j], 32);
    }
    if (q == 0) {
        uint4 o;
        o.x = pack4fp8(SP_OUT * a[0],  SP_OUT * a[1],  SP_OUT * a[2],  SP_OUT * a[3]);
        o.y = pack4fp8(SP_OUT * a[4],  SP_OUT * a[5],  SP_OUT * a[6],  SP_OUT * a[7]);
        o.z = pack4fp8(SP_OUT * a[8],  SP_OUT * a[9],  SP_OUT * a[10], SP_OUT * a[11]);
        o.w = pack4fp8(SP_OUT * a[12], SP_OUT * a[13], SP_OUT * a[14], SP_OUT * a[15]);
        *(uint4*)(cout8 + (size_t)r * H_LAT + l16 * 16) = o;
    }
}

// ---------------- fused classifier: Z = ((emb+c1+c2+c3)/4) @ W_cls + b_cls; log_softmax -------
__global__ void __launch_bounds__(256) cls_kernel(const unsigned short* __restrict__ emb,
                                                  const unsigned char* __restrict__ c1,
                                                  const unsigned char* __restrict__ c2,
                                                  const unsigned char* __restrict__ c3,
                                                  const float* __restrict__ W,
                                                  const float* __restrict__ bc,
                                                  float* __restrict__ out) {
    __shared__ float Wl[H_LAT * N_CLASS];
    __shared__ float bl[N_CLASS];
    for (int i = threadIdx.x; i < H_LAT * N_CLASS; i += 256) Wl[i] = W[i];
    if (threadIdx.x < N_CLASS) bl[threadIdx.x] = bc[threadIdx.x];
    __syncthreads();

    int r = blockIdx.x * 256 + threadIdx.x;
    if (r >= N_NODES) return;

    float Z[N_CLASS];
#pragma unroll
    for (int c = 0; c < N_CLASS; ++c) Z[c] = bl[c];

    const unsigned short* p0 = emb + (size_t)r * H_LAT;
    const unsigned char*  p1 = c1 + (size_t)r * H_LAT;
    const unsigned char*  p2 = c2 + (size_t)r * H_LAT;
    const unsigned char*  p3 = c3 + (size_t)r * H_LAT;

    for (int f = 0; f < H_LAT; f += 8) {
        uint4 ge = *(const uint4*)(p0 + f);
        uint2 h1 = *(const uint2*)(p1 + f);
        uint2 h2 = *(const uint2*)(p2 + f);
        uint2 h3 = *(const uint2*)(p3 + f);
        float af[8];
        floatx2 pa, pb, pc;
        pa = __builtin_amdgcn_cvt_pk_f32_fp8(h1.x, false);
        pb = __builtin_amdgcn_cvt_pk_f32_fp8(h2.x, false);
        pc = __builtin_amdgcn_cvt_pk_f32_fp8(h3.x, false);
        af[0] = 0.25f * (blo(ge.x) + pa[0] * INV1 + pb[0] * INV2 + pc[0] * INV3);
        af[1] = 0.25f * (bhi(ge.x) + pa[1] * INV1 + pb[1] * INV2 + pc[1] * INV3);
        pa = __builtin_amdgcn_cvt_pk_f32_fp8(h1.x, true);
        pb = __builtin_amdgcn_cvt_pk_f32_fp8(h2.x, true);
        pc = __builtin_amdgcn_cvt_pk_f32_fp8(h3.x, true);
        af[2] = 0.25f * (blo(ge.y) + pa[0] * INV1 + pb[0] * INV2 + pc[0] * INV3);
        af[3] = 0.25f * (bhi(ge.y) + pa[1] * INV1 + pb[1] * INV2 + pc[1] * INV3);
        pa = __builtin_amdgcn_cvt_pk_f32_fp8(h1.y, false);
        pb = __builtin_amdgcn_cvt_pk_f32_fp8(h2.y, false);
        pc = __builtin_amdgcn_cvt_pk_f32_fp8(h3.y, false);
        af[4] = 0.25f * (blo(ge.z) + pa[0] * INV1 + pb[0] * INV2 + pc[0] * INV3);
        af[5] = 0.25f * (bhi(ge.z) + pa[1] * INV1 + pb[1] * INV2 + pc[1] * INV3);
        pa = __builtin_amdgcn_cvt_pk_f32_fp8(h1.y, true);
        pb = __builtin_amdgcn_cvt_pk_f32_fp8(h2.y, true);
        pc = __builtin_amdgcn_cvt_pk_f32_fp8(h3.y, true);
        af[6] = 0.25f * (blo(ge.w) + pa[0] * INV1 + pb[0] * INV2 + pc[0] * INV3);
        af[7] = 0.25f * (bhi(ge.w) + pa[1] * INV1 + pb[1] * INV2 + pc[1] * INV3);
#pragma unroll
        for (int j = 0; j < 8; ++j) {
            const float* wrow = &Wl[(f + j) * N_CLASS];
#pragma unroll
            for (int c = 0; c < N_CLASS; ++c) Z[c] = fmaf(af[j], wrow[c], Z[c]);
        }
    }

    float m = Z[0];
#pragma unroll
    for (int c = 1; c < N_CLASS; ++c) m = fmaxf(m, Z[c]);
    float s = 0.f;
#pragma unroll
    for (int c = 0; c < N_CLASS; ++c) s += __expf(Z[c] - m);
    float ls = __logf(s) + m;
#pragma unroll
    for (int c = 0; c < N_CLASS; ++c) out[(size_t)r * N_CLASS + c] = Z[c] - ls;
}

// ---------------- launch ----------------
extern "C" void kernel_launch(void* const* d_in, const int* in_sizes, int n_in,
                              void* d_out, int out_size, void* d_ws, size_t ws_size,
                              hipStream_t stream) {
    const float* X        = (const float*)d_in[0];
    const float* W_red    = (const float*)d_in[1];
    const float* b_red    = (const float*)d_in[2];
    const float* W_cls    = (const float*)d_in[3];
    const float* b_cls    = (const float*)d_in[4];
    const float* e_vals   = (const float*)d_in[5];
    const int*   e_rows   = (const int*)d_in[6];
    const int*   e_cols   = (const int*)d_in[7];
    float* out = (float*)d_out;

    char* p = (char*)d_ws;
    auto carve = [&](size_t bytes) -> void* {
        void* r = (void*)p;
        p += (bytes + 255) & ~(size_t)255;
        return r;
    };
    unsigned short* WT   = (unsigned short*)carve((size_t)H_LAT * D_IN * 2);
    unsigned short* emb  = (unsigned short*)carve((size_t)N_TOTAL * H_LAT * 2);
    unsigned char*  emb8 = (unsigned char*)carve((size_t)N_TOTAL * H_LAT);
    unsigned char*  c1_8 = (unsigned char*)carve((size_t)N_TOTAL * H_LAT);
    unsigned char*  c2_8 = (unsigned char*)carve((size_t)N_TOTAL * H_LAT);
    unsigned char*  c3_8 = (unsigned char*)carve((size_t)N_TOTAL * H_LAT);
    int*   cnt         = (int*)carve((size_t)CNT_PAD * 4);
    int*   row_ptr     = (int*)carve((size_t)CNT_PAD * 4);
    int*   row_ofs     = (int*)carve((size_t)CNT_PAD * 4);
    int*   bucket_fill = (int*)carve((size_t)NB * 4);
    int2*  csr_ev      = (int2*)carve((size_t)NNZ_E * 8);
    int2*  binned      = (int2*)c2_8;   // alias: binned dead after binB, before spmm2 writes c2_8

    hipMemsetAsync(cnt, 0, (size_t)CNT_PAD * 4, stream);

    prep_wt_kernel<<<512, 256, 0, stream>>>(W_red, WT);
    gemm1_kernel<<<(N_TOTAL + 63) / 64, 256, 0, stream>>>(X, WT, b_red, emb);
    conv8_kernel<<<(N_TOTAL * H_LAT / 8 + 255) / 256, 256, 0, stream>>>(emb, emb8);

    hist_kernel<<<(NNZ_E / 4 + 255) / 256, 256, 0, stream>>>(e_rows, cnt);
    scan_kernel<<<1, 1024, 0, stream>>>(cnt, row_ptr, row_ofs);
    initfill_kernel<<<(NB + 255) / 256, 256, 0, stream>>>(row_ptr, bucket_fill);
    binA_kernel<<<(NNZ_E + CH - 1) / CH, 256, 0, stream>>>(e_rows, e_cols, e_vals, bucket_fill, binned);
    binB_kernel<<<NB, 256, 0, stream>>>(row_ptr, binned, row_ofs, csr_ev);

    spmm8_kernel<<<N_TOTAL / 4, 256, 0, stream>>>(emb8, c1_8, row_ptr, csr_ev, N_TOTAL);
    spmm8_kernel<<<N_TOTAL / 4, 256, 0, stream>>>(c1_8, c2_8, row_ptr, csr_ev, N_TOTAL);
    spmm8_kernel<<<N_NODES / 4, 256, 0, stream>>>(c2_8, c3_8, row_ptr, csr_ev, N_NODES);

    cls_kernel<<<(N_NODES + 255) / 256, 256, 0, stream>>>(emb, c1_8, c2_8, c3_8, W_cls, b_cls, out);
}

// Round 5
// 1556.705 us; speedup vs baseline: 1.6988x; 1.0224x over previous
//
#include <hip/hip_runtime.h>

#define N_NODES 100000
#define M_HYPER 50000
#define N_TOTAL 150000
#define D_IN    512
#define H_LAT   256
#define N_CLASS 40
#define NNZ_E   4800000
#define CNT_PAD 151552   // 37 * 4096, >= N_TOTAL+1
#define BK      128
#define BROWS   256
#define NB      ((N_TOTAL + BROWS - 1) / BROWS)   // 586 buckets
#define CH      4096

// layer scales: emb8 = 16*emb; each spmm stores 8*a (a already carries input scale)
// => c1_8 = 128*c1, c2_8 = 1024*c2, c3_8 = 8192*c3
#define S_EMB   16.0f
#define SP_OUT  8.0f
#define INV1    (1.0f / 128.0f)
#define INV2    (1.0f / 1024.0f)
#define INV3    (1.0f / 8192.0f)

typedef float  floatx4 __attribute__((ext_vector_type(4)));
typedef float  floatx2 __attribute__((ext_vector_type(2)));
typedef __bf16 bf16x8  __attribute__((ext_vector_type(8)));

__device__ __forceinline__ unsigned short bf16_rne(float f) {
    unsigned u = __float_as_uint(f);
    return (unsigned short)((u + 0x7FFFu + ((u >> 16) & 1u)) >> 16);
}
__device__ __forceinline__ float blo(unsigned w) { return __uint_as_float(w << 16); }
__device__ __forceinline__ float bhi(unsigned w) { return __uint_as_float(w & 0xFFFF0000u); }

__device__ __forceinline__ unsigned pack4fp8(float f0, float f1, float f2, float f3) {
    int d = __builtin_amdgcn_cvt_pk_fp8_f32(f0, f1, 0, false);
    d = __builtin_amdgcn_cvt_pk_fp8_f32(f2, f3, d, true);
    return (unsigned)d;
}

// ---------------- W_red transpose + bf16 convert: W[512][256] -> WT[256][512] ----------------
__global__ void __launch_bounds__(256) prep_wt_kernel(const float* __restrict__ W,
                                                      unsigned short* __restrict__ WT) {
    int t = blockIdx.x * 256 + threadIdx.x;
    if (t < D_IN * H_LAT) {
        int k = t >> 8;
        int n = t & 255;
        WT[n * D_IN + k] = bf16_rne(W[t]);
    }
}

// ---------------- GEMM1: emb = X @ W_red + b_red  (LDS-tiled bf16 MFMA) ----------------------
// 256 thr, tile 64 rows x 256 cols, BK=128. Register-prefetch double buffering: next A-chunk's
// global loads issue BEFORE the MFMA phase so HBM latency overlaps compute instead of being
// exposed at the barrier. Epilogue: acc -> LDS (row-major) -> coalesced uint4 stores of
// bf16 (rows < N_NODES only; cls never reads hyperedge rows) + fused fp8 conversion (all rows).
__global__ void __launch_bounds__(256, 3) gemm1_kernel(const float* __restrict__ X,
                                                       const unsigned short* __restrict__ WT,
                                                       const float* __restrict__ brd,
                                                       unsigned short* __restrict__ emb,
                                                       unsigned char* __restrict__ emb8) {
    __shared__ __align__(16) unsigned short smem[64 * (H_LAT + 8)];   // 33.8 KB
    unsigned short (*As)[BK + 8]    = (unsigned short (*)[BK + 8])smem;
    unsigned short (*Cs)[H_LAT + 8] = (unsigned short (*)[H_LAT + 8])smem;

    int tid  = threadIdx.x;
    int wv   = tid >> 6;
    int lane = tid & 63;
    int l16  = lane & 15;
    int quad = lane >> 4;
    int row0 = blockIdx.x * 64;

    int cst = (tid & 31) << 2;   // staging col (float idx), fixed per thread
    int rst = tid >> 5;          // staging row base 0..7
    const float* xbase = X + cst;

    float4 pf[8];
#pragma unroll
    for (int j = 0; j < 8; ++j) {
        int gr = min(row0 + rst + 8 * j, N_TOTAL - 1);
        pf[j] = *(const float4*)(xbase + (size_t)gr * D_IN);
    }

    floatx4 acc[4][4];
#pragma unroll
    for (int a = 0; a < 4; ++a)
#pragma unroll
        for (int b = 0; b < 4; ++b) acc[a][b] = (floatx4)0.f;

#pragma unroll 1
    for (int k0 = 0; k0 < D_IN; k0 += BK) {
        // regs (chunk k0) -> LDS as bf16
#pragma unroll
        for (int j = 0; j < 8; ++j) {
            ushort4 u;
            u.x = bf16_rne(pf[j].x); u.y = bf16_rne(pf[j].y);
            u.z = bf16_rne(pf[j].z); u.w = bf16_rne(pf[j].w);
            *(ushort4*)(&As[rst + 8 * j][cst]) = u;
        }
        __syncthreads();
        // issue next chunk's global loads now; they land during the MFMA phase below
        if (k0 + BK < D_IN) {
#pragma unroll
            for (int j = 0; j < 8; ++j) {
                int gr = min(row0 + rst + 8 * j, N_TOTAL - 1);
                pf[j] = *(const float4*)(xbase + (size_t)gr * D_IN + k0 + BK);
            }
        }
#pragma unroll
        for (int ks = 0; ks < BK; ks += 32) {
            bf16x8 af[4];
#pragma unroll
            for (int rt = 0; rt < 4; ++rt)
                af[rt] = *(const bf16x8*)(&As[rt * 16 + l16][ks + quad * 8]);
#pragma unroll
            for (int ct = 0; ct < 4; ++ct) {
                int col = wv * 64 + ct * 16 + l16;
                bf16x8 bw = *(const bf16x8*)(WT + (size_t)col * D_IN + k0 + ks + quad * 8);
#pragma unroll
                for (int rt = 0; rt < 4; ++rt)
                    acc[rt][ct] = __builtin_amdgcn_mfma_f32_16x16x32_bf16(af[rt], bw, acc[rt][ct], 0, 0, 0);
            }
        }
        __syncthreads();
    }

    // acc (+bias) -> LDS row-major
#pragma unroll
    for (int ct = 0; ct < 4; ++ct) {
        int col = wv * 64 + ct * 16 + l16;
        float bias = brd[col];
#pragma unroll
        for (int rt = 0; rt < 4; ++rt)
#pragma unroll
            for (int r = 0; r < 4; ++r)
                Cs[rt * 16 + quad * 4 + r][col] = bf16_rne(acc[rt][ct][r] + bias);
    }
    __syncthreads();

    // bf16 store, coalesced uint4, only rows < N_NODES
    int nbf = N_NODES - row0;
#pragma unroll
    for (int j = 0; j < 8; ++j) {
        int idx = tid + 256 * j;
        int r = idx >> 5;
        int cq = (idx & 31) * 8;
        if (r < nbf)
            *(uint4*)(emb + (size_t)(row0 + r) * H_LAT + cq) = *(const uint4*)(&Cs[r][cq]);
    }
    // fp8 store, coalesced uint4, all valid rows
#pragma unroll
    for (int j = 0; j < 4; ++j) {
        int idx = tid + 256 * j;
        int r = idx >> 4;
        int cq = (idx & 15) * 16;
        if (row0 + r < N_TOTAL) {
            const unsigned short* s = &Cs[r][cq];
            uint4 w0 = *(const uint4*)s;
            uint4 w1 = *(const uint4*)(s + 8);
            uint4 o;
            o.x = pack4fp8(S_EMB * blo(w0.x), S_EMB * bhi(w0.x), S_EMB * blo(w0.y), S_EMB * bhi(w0.y));
            o.y = pack4fp8(S_EMB * blo(w0.z), S_EMB * bhi(w0.z), S_EMB * blo(w0.w), S_EMB * bhi(w0.w));
            o.z = pack4fp8(S_EMB * blo(w1.x), S_EMB * bhi(w1.x), S_EMB * blo(w1.y), S_EMB * bhi(w1.y));
            o.w = pack4fp8(S_EMB * blo(w1.z), S_EMB * bhi(w1.z), S_EMB * blo(w1.w), S_EMB * bhi(w1.w));
            *(uint4*)(emb8 + (size_t)(row0 + r) * H_LAT + cq) = o;
        }
    }
}

// ---------------- CSR build ----------------
__global__ void __launch_bounds__(256) hist_kernel(const int* __restrict__ rows, int* __restrict__ cnt) {
    int t = blockIdx.x * 256 + threadIdx.x;
    if (t < NNZ_E / 4) {
        int4 r = ((const int4*)rows)[t];
        atomicAdd(&cnt[r.x], 1);
        atomicAdd(&cnt[r.y], 1);
        atomicAdd(&cnt[r.z], 1);
        atomicAdd(&cnt[r.w], 1);
    }
}

__global__ void __launch_bounds__(1024) scan_kernel(const int* __restrict__ cnt,
                                                    int* __restrict__ row_ptr,
                                                    int* __restrict__ row_ofs) {
    __shared__ int wsum[16];
    int tid = threadIdx.x;
    int lane = tid & 63, wid = tid >> 6;
    int running = 0;
    for (int base = 0; base < CNT_PAD; base += 4096) {
        int idx = base + tid * 4;
        int4 v = *(const int4*)(cnt + idx);
        int t0 = v.x, t1 = t0 + v.y, t2 = t1 + v.z, t3 = t2 + v.w;
        int tsum = t3;
        int s = tsum;
#pragma unroll
        for (int d = 1; d < 64; d <<= 1) {
            int o = __shfl_up(s, d);
            if (lane >= d) s += o;
        }
        if (lane == 63) wsum[wid] = s;
        __syncthreads();
        if (wid == 0) {
            int ws = (lane < 16) ? wsum[lane] : 0;
#pragma unroll
            for (int d = 1; d < 16; d <<= 1) {
                int o = __shfl_up(ws, d);
                if (lane >= d) ws += o;
            }
            if (lane < 16) wsum[lane] = ws;
        }
        __syncthreads();
        int waveoff = (wid == 0) ? 0 : wsum[wid - 1];
        int total   = wsum[15];
        int eb = running + waveoff + (s - tsum);
        int4 o4 = make_int4(eb, eb + t0, eb + t1, eb + t2);
        *(int4*)(row_ptr + idx) = o4;
        *(int4*)(row_ofs + idx) = o4;
        running += total;
        __syncthreads();
    }
}

__global__ void __launch_bounds__(256) initfill_kernel(const int* __restrict__ row_ptr,
                                                       int* __restrict__ bucket_fill) {
    int b = blockIdx.x * 256 + threadIdx.x;
    if (b < NB) bucket_fill[b] = row_ptr[min(b * BROWS, N_TOTAL)];
}

// Phase A: bin edges into 586 coarse buckets (contiguous runs per block-bin -> compact writes)
__global__ void __launch_bounds__(256) binA_kernel(const int* __restrict__ rows,
                                                   const int* __restrict__ cols,
                                                   const float* __restrict__ vals,
                                                   int* __restrict__ bucket_fill,
                                                   int2* __restrict__ binned) {
    __shared__ int hist[NB];
    int tid = threadIdx.x;
    long base = (long)blockIdx.x * CH;
    for (int i = tid; i < NB; i += 256) hist[i] = 0;
    __syncthreads();

    int mybkt[16];
    int myrl[16];
#pragma unroll
    for (int j = 0; j < 16; ++j) {
        long e = base + j * 256 + tid;
        int b = -1, rl = 0;
        if (e < NNZ_E) {
            int r = rows[e];
            b = r >> 8;
            rl = r & 255;
            atomicAdd(&hist[b], 1);
        }
        mybkt[j] = b; myrl[j] = rl;
    }
    __syncthreads();
    for (int b = tid; b < NB; b += 256) {
        int c = hist[b];
        int g = 0;
        if (c > 0) g = atomicAdd(&bucket_fill[b], c);
        hist[b] = g;
    }
    __syncthreads();
#pragma unroll
    for (int j = 0; j < 16; ++j) {
        long e = base + j * 256 + tid;
        if (e < NNZ_E) {
            int b = mybkt[j];
            int pos = atomicAdd(&hist[b], 1);
            int c = cols[e];
            float v = vals[e];
            binned[pos] = make_int2(c | (myrl[j] << 18), __float_as_int(v));
        }
    }
}

// Phase B: fine scatter within one bucket per block (random writes confined to ~64 KB, L2-hot)
__global__ void __launch_bounds__(256) binB_kernel(const int* __restrict__ row_ptr,
                                                   const int2* __restrict__ binned,
                                                   int* __restrict__ row_ofs,
                                                   int2* __restrict__ csr_ev) {
    int b = blockIdx.x;
    int s = row_ptr[b * BROWS];
    int e = row_ptr[min((b + 1) * BROWS, N_TOTAL)];
    int rbase = b << 8;
    for (int t = s + (int)threadIdx.x; t < e; t += 256) {
        int2 w = binned[t];
        int rl  = ((unsigned)w.x) >> 18;
        int col = w.x & 0x3FFFF;
        int p = atomicAdd(&row_ofs[rbase + rl], 1);
        csr_ev[p] = make_int2(col, w.y);
    }
}

// ---------------- SpMM (fp8): cout8[r,:] = SP_OUT * sum_e val[e] * cin8[col[e],:] --------------
__global__ void __launch_bounds__(256) spmm8_kernel(const unsigned char* __restrict__ cin8,
                                                    unsigned char* __restrict__ cout8,
                                                    const int* __restrict__ row_ptr,
                                                    const int2* __restrict__ csr_ev,
                                                    int nrows) {
    int r = (blockIdx.x * 256 + threadIdx.x) >> 6;
    if (r >= nrows) return;
    int lane = threadIdx.x & 63;
    int q   = lane >> 4;
    int l16 = lane & 15;
    int beg = row_ptr[r], end = row_ptr[r + 1];

    float a[16];
#pragma unroll
    for (int j = 0; j < 16; ++j) a[j] = 0.f;
    const unsigned char* basep = cin8 + l16 * 16;

    for (int b = beg; b < end; b += 64) {
        int e = b + lane;
        int2 ev = (e < end) ? csr_ev[e] : make_int2(0, 0);  // col 0 / val 0 -> harmless
        int n = min(64, end - b);
        for (int i = 0; i < n; i += 16) {
            int cc[4]; float vv[4]; uint4 g[4];
#pragma unroll
            for (int u = 0; u < 4; ++u) {
                int src = i + 4 * u + q;
                cc[u] = __shfl(ev.x, src);
                vv[u] = __uint_as_float((unsigned)__shfl(ev.y, src));
            }
#pragma unroll
            for (int u = 0; u < 4; ++u) {
                if (i + 4 * u < n) g[u] = *(const uint4*)(basep + (size_t)cc[u] * H_LAT);
                else               g[u] = make_uint4(0, 0, 0, 0);
            }
#pragma unroll
            for (int u = 0; u < 4; ++u) {
                floatx2 p;
                p = __builtin_amdgcn_cvt_pk_f32_fp8(g[u].x, false); a[0]  = fmaf(vv[u], p[0], a[0]);  a[1]  = fmaf(vv[u], p[1], a[1]);
                p = __builtin_amdgcn_cvt_pk_f32_fp8(g[u].x, true);  a[2]  = fmaf(vv[u], p[0], a[2]);  a[3]  = fmaf(vv[u], p[1], a[3]);
                p = __builtin_amdgcn_cvt_pk_f32_fp8(g[u].y, false); a[4]  = fmaf(vv[u], p[0], a[4]);  a[5]  = fmaf(vv[u], p[1], a[5]);
                p = __builtin_amdgcn_cvt_pk_f32_fp8(g[u].y, true);  a[6]  = fmaf(vv[u], p[0], a[6]);  a[7]  = fmaf(vv[u], p[1], a[7]);
                p = __builtin_amdgcn_cvt_pk_f32_fp8(g[u].z, false); a[8]  = fmaf(vv[u], p[0], a[8]);  a[9]  = fmaf(vv[u], p[1], a[9]);
                p = __builtin_amdgcn_cvt_pk_f32_fp8(g[u].z, true);  a[10] = fmaf(vv[u], p[0], a[10]); a[11] = fmaf(vv[u], p[1], a[11]);
                p = __builtin_amdgcn_cvt_pk_f32_fp8(g[u].w, false); a[12] = fmaf(vv[u], p[0], a[12]); a[13] = fmaf(vv[u], p[1], a[13]);
                p = __builtin_amdgcn_cvt_pk_f32_fp8(g[u].w, true);  a[14] = fmaf(vv[u], p[0], a[14]); a[15] = fmaf(vv[u], p[1], a[15]);
            }
        }
    }
#pragma unroll
    for (int j = 0; j < 16; ++j) {
        a[j] += __shfl_xor(a[j], 16);
        a[j] += __shfl_xor(a[j], 32);
    }
    if (q == 0) {
        uint4 o;
        o.x = pack4fp8(SP_OUT * a[0],  SP_OUT * a[1],  SP_OUT * a[2],  SP_OUT * a[3]);
        o.y = pack4fp8(SP_OUT * a[4],  SP_OUT * a[5],  SP_OUT * a[6],  SP_OUT * a[7]);
        o.z = pack4fp8(SP_OUT * a[8],  SP_OUT * a[9],  SP_OUT * a[10], SP_OUT * a[11]);
        o.w = pack4fp8(SP_OUT * a[12], SP_OUT * a[13], SP_OUT * a[14], SP_OUT * a[15]);
        *(uint4*)(cout8 + (size_t)r * H_LAT + l16 * 16) = o;
    }
}

// ---------------- fused classifier: Z = ((emb+c1+c2+c3)/4) @ W_cls + b_cls; log_softmax -------
__global__ void __launch_bounds__(256) cls_kernel(const unsigned short* __restrict__ emb,
                                                  const unsigned char* __restrict__ c1,
                                                  const unsigned char* __restrict__ c2,
                                                  const unsigned char* __restrict__ c3,
                                                  const float* __restrict__ W,
                                                  const float* __restrict__ bc,
                                                  float* __restrict__ out) {
    __shared__ float Wl[H_LAT * N_CLASS];
    __shared__ float bl[N_CLASS];
    for (int i = threadIdx.x; i < H_LAT * N_CLASS; i += 256) Wl[i] = W[i];
    if (threadIdx.x < N_CLASS) bl[threadIdx.x] = bc[threadIdx.x];
    __syncthreads();

    int r = blockIdx.x * 256 + threadIdx.x;
    if (r >= N_NODES) return;

    float Z[N_CLASS];
#pragma unroll
    for (int c = 0; c < N_CLASS; ++c) Z[c] = bl[c];

    const unsigned short* p0 = emb + (size_t)r * H_LAT;
    const unsigned char*  p1 = c1 + (size_t)r * H_LAT;
    const unsigned char*  p2 = c2 + (size_t)r * H_LAT;
    const unsigned char*  p3 = c3 + (size_t)r * H_LAT;

    for (int f = 0; f < H_LAT; f += 8) {
        uint4 ge = *(const uint4*)(p0 + f);
        uint2 h1 = *(const uint2*)(p1 + f);
        uint2 h2 = *(const uint2*)(p2 + f);
        uint2 h3 = *(const uint2*)(p3 + f);
        float af[8];
        floatx2 pa, pb, pc;
        pa = __builtin_amdgcn_cvt_pk_f32_fp8(h1.x, false);
        pb = __builtin_amdgcn_cvt_pk_f32_fp8(h2.x, false);
        pc = __builtin_amdgcn_cvt_pk_f32_fp8(h3.x, false);
        af[0] = 0.25f * (blo(ge.x) + pa[0] * INV1 + pb[0] * INV2 + pc[0] * INV3);
        af[1] = 0.25f * (bhi(ge.x) + pa[1] * INV1 + pb[1] * INV2 + pc[1] * INV3);
        pa = __builtin_amdgcn_cvt_pk_f32_fp8(h1.x, true);
        pb = __builtin_amdgcn_cvt_pk_f32_fp8(h2.x, true);
        pc = __builtin_amdgcn_cvt_pk_f32_fp8(h3.x, true);
        af[2] = 0.25f * (blo(ge.y) + pa[0] * INV1 + pb[0] * INV2 + pc[0] * INV3);
        af[3] = 0.25f * (bhi(ge.y) + pa[1] * INV1 + pb[1] * INV2 + pc[1] * INV3);
        pa = __builtin_amdgcn_cvt_pk_f32_fp8(h1.y, false);
        pb = __builtin_amdgcn_cvt_pk_f32_fp8(h2.y, false);
        pc = __builtin_amdgcn_cvt_pk_f32_fp8(h3.y, false);
        af[4] = 0.25f * (blo(ge.z) + pa[0] * INV1 + pb[0] * INV2 + pc[0] * INV3);
        af[5] = 0.25f * (bhi(ge.z) + pa[1] * INV1 + pb[1] * INV2 + pc[1] * INV3);
        pa = __builtin_amdgcn_cvt_pk_f32_fp8(h1.y, true);
        pb = __builtin_amdgcn_cvt_pk_f32_fp8(h2.y, true);
        pc = __builtin_amdgcn_cvt_pk_f32_fp8(h3.y, true);
        af[6] = 0.25f * (blo(ge.w) + pa[0] * INV1 + pb[0] * INV2 + pc[0] * INV3);
        af[7] = 0.25f * (bhi(ge.w) + pa[1] * INV1 + pb[1] * INV2 + pc[1] * INV3);
#pragma unroll
        for (int j = 0; j < 8; ++j) {
            const float* wrow = &Wl[(f + j) * N_CLASS];
#pragma unroll
            for (int c = 0; c < N_CLASS; ++c) Z[c] = fmaf(af[j], wrow[c], Z[c]);
        }
    }

    float m = Z[0];
#pragma unroll
    for (int c = 1; c < N_CLASS; ++c) m = fmaxf(m, Z[c]);
    float s = 0.f;
#pragma unroll
    for (int c = 0; c < N_CLASS; ++c) s += __expf(Z[c] - m);
    float ls = __logf(s) + m;
#pragma unroll
    for (int c = 0; c < N_CLASS; ++c) out[(size_t)r * N_CLASS + c] = Z[c] - ls;
}

// ---------------- launch ----------------
extern "C" void kernel_launch(void* const* d_in, const int* in_sizes, int n_in,
                              void* d_out, int out_size, void* d_ws, size_t ws_size,
                              hipStream_t stream) {
    const float* X        = (const float*)d_in[0];
    const float* W_red    = (const float*)d_in[1];
    const float* b_red    = (const float*)d_in[2];
    const float* W_cls    = (const float*)d_in[3];
    const float* b_cls    = (const float*)d_in[4];
    const float* e_vals   = (const float*)d_in[5];
    const int*   e_rows   = (const int*)d_in[6];
    const int*   e_cols   = (const int*)d_in[7];
    float* out = (float*)d_out;

    char* p = (char*)d_ws;
    auto carve = [&](size_t bytes) -> void* {
        void* r = (void*)p;
        p += (bytes + 255) & ~(size_t)255;
        return r;
    };
    unsigned short* WT   = (unsigned short*)carve((size_t)H_LAT * D_IN * 2);
    unsigned short* emb  = (unsigned short*)carve((size_t)N_TOTAL * H_LAT * 2);
    unsigned char*  emb8 = (unsigned char*)carve((size_t)N_TOTAL * H_LAT);
    unsigned char*  c1_8 = (unsigned char*)carve((size_t)N_TOTAL * H_LAT);
    unsigned char*  c2_8 = (unsigned char*)carve((size_t)N_TOTAL * H_LAT);
    unsigned char*  c3_8 = (unsigned char*)carve((size_t)N_TOTAL * H_LAT);
    int*   cnt         = (int*)carve((size_t)CNT_PAD * 4);
    int*   row_ptr     = (int*)carve((size_t)CNT_PAD * 4);
    int*   row_ofs     = (int*)carve((size_t)CNT_PAD * 4);
    int*   bucket_fill = (int*)carve((size_t)NB * 4);
    int2*  csr_ev      = (int2*)carve((size_t)NNZ_E * 8);
    int2*  binned      = (int2*)c2_8;   // alias: binned dead after binB, before spmm2 writes c2_8

    hipMemsetAsync(cnt, 0, (size_t)CNT_PAD * 4, stream);

    prep_wt_kernel<<<512, 256, 0, stream>>>(W_red, WT);
    gemm1_kernel<<<(N_TOTAL + 63) / 64, 256, 0, stream>>>(X, WT, b_red, emb, emb8);

    hist_kernel<<<(NNZ_E / 4 + 255) / 256, 256, 0, stream>>>(e_rows, cnt);
    scan_kernel<<<1, 1024, 0, stream>>>(cnt, row_ptr, row_ofs);
    initfill_kernel<<<(NB + 255) / 256, 256, 0, stream>>>(row_ptr, bucket_fill);
    binA_kernel<<<(NNZ_E + CH - 1) / CH, 256, 0, stream>>>(e_rows, e_cols, e_vals, bucket_fill, binned);
    binB_kernel<<<NB, 256, 0, stream>>>(row_ptr, binned, row_ofs, csr_ev);

    spmm8_kernel<<<N_TOTAL / 4, 256, 0, stream>>>(emb8, c1_8, row_ptr, csr_ev, N_TOTAL);
    spmm8_kernel<<<N_TOTAL / 4, 256, 0, stream>>>(c1_8, c2_8, row_ptr, csr_ev, N_TOTAL);
    spmm8_kernel<<<N_NODES / 4, 256, 0, stream>>>(c2_8, c3_8, row_ptr, csr_ev, N_NODES);

    cls_kernel<<<(N_NODES + 255) / 256, 256, 0, stream>>>(emb, c1_8, c2_8, c3_8, W_cls, b_cls, out);
}